// Round 15
// baseline (123.701 us; speedup 1.0000x reference)
//
#include <hip/hip_runtime.h>
#include <hip/hip_bf16.h>
#include <cstddef>

#define H_ 128
#define W_ 128
#define HW_ 16384
#define C_ 64
#define B_ 8
#define EPS_ 1e-5f

#define KSLOTS 19   // deform GEMM k-slots, k = kk*68 + c (c<64 data, 64..67 pad)
#define ROWS 616    // sAb row stride (shorts)
#define TSTR 72     // tile row stride (shorts) = 9 granules of 16B

typedef __attribute__((ext_vector_type(8))) short bf16x8;
typedef __attribute__((ext_vector_type(4))) float f32x4;

__device__ __forceinline__ unsigned short f2bf(float f) {
  __hip_bfloat16 h = __float2bfloat16(f);
  unsigned short u;
  __builtin_memcpy(&u, &h, 2);
  return u;
}
__device__ __forceinline__ unsigned pack2(float lo, float hi) {
  return (unsigned)f2bf(lo) | ((unsigned)f2bf(hi) << 16);
}
__device__ __forceinline__ float bfl(unsigned short v) {
  return __uint_as_float(((unsigned)v) << 16);
}

// ---------------- prep: pack ALL GEMM weights (proven) ----------------------
__global__ __launch_bounds__(256) void prep_kernel(
    const float* __restrict__ dw, const float* __restrict__ offw,
    const float* __restrict__ w1, const float* __restrict__ b1,
    const float* __restrict__ gamma, const float* __restrict__ beta,
    const float* __restrict__ rmean, const float* __restrict__ rvar,
    const float* __restrict__ w2,
    unsigned short* __restrict__ wf2, unsigned short* __restrict__ offwp,
    unsigned short* __restrict__ w1p, unsigned short* __restrict__ w2p,
    float* __restrict__ b1f) {
  int i = blockIdx.x * 256 + threadIdx.x;
  if (i < 38912) {  // deform: 19 sg * 4 og * 64 l * 8 j, k = kk*68 + c
    int j = i & 7, l = (i >> 3) & 63, og = (i >> 9) & 3, sg = i >> 11;
    int o = og * 16 + (l & 15);
    int k = sg * 32 + ((l >> 4) << 3) + j;
    int kk = k / 68, c = k - kk * 68;
    float v = (c < 64) ? dw[o * 576 + c * 9 + kk] : 0.f;
    wf2[i] = f2bf(v);
  } else if (i < 38912 + 18432) {  // offconv: 18 slot * 2 og * 64 l * 8 j
    int j2 = i - 38912;
    int j = j2 & 7, l = (j2 >> 3) & 63, og = (j2 >> 9) & 1, slot = j2 >> 10;
    int kk = slot >> 1, s = slot & 1;
    int oc = og * 16 + (l & 15);
    int c = s * 32 + ((l >> 4) << 3) + j;
    float v = (oc < 18) ? offw[oc * 576 + c * 9 + kk] : 0.f;
    offwp[j2] = f2bf(v);
  } else if (i < 38912 + 18432 + 4096) {
    int j2 = i - 38912 - 18432;
    int j = j2 & 7, l = (j2 >> 3) & 63, og = (j2 >> 9) & 3, sg = j2 >> 11;
    int o = og * 16 + (l & 15);
    int c = sg * 32 + ((l >> 4) << 3) + j;
    float inv = gamma[o] * rsqrtf(rvar[o] + EPS_);
    w1p[j2] = f2bf(w1[o * 64 + c] * inv);
  } else if (i < 38912 + 18432 + 8192) {
    int j2 = i - 38912 - 18432 - 4096;
    int j = j2 & 7, l = (j2 >> 3) & 63, og = (j2 >> 9) & 3, sg = j2 >> 11;
    int o = og * 16 + (l & 15);
    int c = sg * 32 + ((l >> 4) << 3) + j;
    w2p[j2] = f2bf(w2[o * 64 + c]);
  } else if (i < 38912 + 18432 + 8192 + 64) {
    int o = i - 38912 - 18432 - 8192;
    float inv = gamma[o] * rsqrtf(rvar[o] + EPS_);
    b1f[o] = b1[o] * inv + beta[o] - rmean[o] * inv;
  }
}

// ---------------- avg pool 3x3 -> NHWC bf16 (R14, proven) ----------------
__global__ __launch_bounds__(256) void avgpool_kernel(const float* __restrict__ xin,
                                                      unsigned short* __restrict__ pbf) {
  __shared__ __align__(16) unsigned short pool[64 * 72];
  int t = threadIdx.x;
  int c = t & 63, wvp = t >> 6;
  int blk = blockIdx.x;
  int half = blk & 1;
  int row = blk >> 1;
  int b = row >> 7, y = row & 127;
  int xb = half * 64 + wvp * 16;
  const float* q = xin + (size_t)(b * C_ + c) * HW_;

  float ver[16];
#pragma unroll
  for (int i = 0; i < 16; ++i) ver[i] = 0.f;
#pragma unroll
  for (int dy = -1; dy <= 1; ++dy) {
    int yy = y + dy;
    if ((unsigned)yy < 128u) {
      const float* r = q + yy * W_;
      float m[18];
      m[0] = (xb > 0) ? r[xb - 1] : 0.f;
      float4 v0 = *(const float4*)(r + xb);
      float4 v1 = *(const float4*)(r + xb + 4);
      float4 v2 = *(const float4*)(r + xb + 8);
      float4 v3 = *(const float4*)(r + xb + 12);
      m[1] = v0.x; m[2] = v0.y; m[3] = v0.z; m[4] = v0.w;
      m[5] = v1.x; m[6] = v1.y; m[7] = v1.z; m[8] = v1.w;
      m[9] = v2.x; m[10] = v2.y; m[11] = v2.z; m[12] = v2.w;
      m[13] = v3.x; m[14] = v3.y; m[15] = v3.z; m[16] = v3.w;
      m[17] = (xb < 112) ? r[xb + 16] : 0.f;
#pragma unroll
      for (int i = 0; i < 16; ++i) ver[i] += m[i] + m[i + 1] + m[i + 2];
    }
  }
  int pxb = wvp * 16;
#pragma unroll
  for (int i = 0; i < 16; ++i) {
    int px = pxb + i;
    int cg = c >> 3;
    pool[px * 72 + ((cg ^ (px & 7)) << 3) + (c & 7)] = f2bf(ver[i] * (1.f / 9.f));
  }
  __syncthreads();

  size_t base = ((size_t)(b * HW_) + y * W_ + half * 64) * 64;
#pragma unroll
  for (int k = 0; k < 2; ++k) {
    int ch = k * 256 + t;
    int px = ch >> 3, g = ch & 7;
    uint2 v = *(const uint2*)(pool + px * 72 + ((g ^ (px & 7)) << 3));
    uint2 v2 = *(const uint2*)(pool + px * 72 + ((g ^ (px & 7)) << 3) + 4);
    *(uint4*)(pbf + base + px * 64 + g * 8) = make_uint4(v.x, v.y, v2.x, v2.y);
  }
}

// ------- fully fused: offconv(MFMA, all waves) + sample + GEMM + tail -------
// Tile: UNCLAMPED origin (ty=y-2, tx=x0-2), zero-filled OOB = conv padding.
// Clamped sample corners provably lie inside the window.
__global__ __launch_bounds__(256, 3) void deform_kernel(
    const unsigned short* __restrict__ pbf,
    const unsigned short* __restrict__ wf2, const unsigned short* __restrict__ offwp,
    const unsigned short* __restrict__ w1p, const unsigned short* __restrict__ w2p,
    const float* __restrict__ offb, const float* __restrict__ db,
    const float* __restrict__ b1f, const float* __restrict__ b2,
    const float* __restrict__ xin, float* __restrict__ out) {
  __shared__ __align__(16) unsigned short tileTb[100 * TSTR];  // 14400 B
  __shared__ __align__(16) unsigned short sAb[16 * ROWS];      // 19712 B
  __shared__ __align__(16) float redO[4 * 64 * 4];             // 4096 B
  __shared__ __align__(16) unsigned short rTb[16 * 72];        // 2304 B
  __shared__ __align__(16) unsigned short hTb[16 * 72];        // 2304 B
  __shared__ uint2 cwb[144];                                   // 1152 B
  __shared__ uchar4 rel4[144];                                 // 576 B
  __shared__ int wOK[4];
  int t = threadIdx.x;
  int lane = t & 63, wv = t >> 6;
  int l15 = lane & 15, lp = lane >> 4;
  int pix0 = blockIdx.x * 16;
  int b = pix0 >> 14;
  int yx0 = pix0 & 16383;
  int y = yx0 >> 7, x0 = yx0 & 127;
  int ty = y - 2, tx = x0 - 2;  // UNclamped
  const unsigned short* pB = pbf + (size_t)(b * HW_) * 64;

  int o_me = wv * 16 + l15;
  int px0 = lp * 4;
  const float4 xv = *(const float4*)(xin + (size_t)(b * C_ + o_me) * HW_ + yx0 + px0);

  // ---- Phase 0: stage tile, zero-filled OOB (800 chunks of 16B) ----
#pragma unroll
  for (int it = 0; it < 3; ++it) {
    int ch = it * 256 + t;
    int rc = ch >> 3, g = ch & 7;
    int r = rc / 20, cx = rc - r * 20;
    int iy = ty + r, ix = tx + cx;
    uint4 v = make_uint4(0u, 0u, 0u, 0u);
    if (((unsigned)iy < 128u) && ((unsigned)ix < 128u)) {
      v = *(const uint4*)(pB + ((size_t)(iy * W_ + ix)) * 64 + g * 8);
    }
    *(uint4*)(tileTb + rc * TSTR + ((g ^ (rc & 7)) << 3)) = v;
  }
  if (t < 32) {
    int ch = 768 + t;
    int rc = ch >> 3, g = ch & 7;
    int r = rc / 20, cx = rc - r * 20;
    int iy = ty + r, ix = tx + cx;
    uint4 v = make_uint4(0u, 0u, 0u, 0u);
    if (((unsigned)iy < 128u) && ((unsigned)ix < 128u)) {
      v = *(const uint4*)(pB + ((size_t)(iy * W_ + ix)) * 64 + g * 8);
    }
    *(uint4*)(tileTb + rc * TSTR + ((g ^ (rc & 7)) << 3)) = v;
  }
  __syncthreads();

  // ---- Phase 1: offconv MFMA, slot-split across all 4 waves ----
  {
    int og = wv & 1, shalf = wv >> 1;
    f32x4 aco = (f32x4){0.f, 0.f, 0.f, 0.f};
    const bf16x8* ofp = (const bf16x8*)offwp;
#pragma unroll
    for (int si = 0; si < 9; ++si) {
      int slot = shalf * 9 + si;
      int kk = slot >> 1, s = slot & 1;
      int rc = (1 + kk / 3) * 20 + (1 + (kk % 3)) + l15;  // pixel row l15 tap
      int ga = s * 4 + lp;
      bf16x8 a = *(const bf16x8*)(tileTb + rc * TSTR + ((ga ^ (rc & 7)) << 3));
      bf16x8 bw = ofp[(slot * 2 + og) * 64 + lane];
      aco = __builtin_amdgcn_mfma_f32_16x16x32_bf16(a, bw, aco, 0, 0, 0);
    }
    *(f32x4*)&redO[(wv * 64 + lane) * 4] = aco;
  }
  __syncthreads();

  // ---- Phase 2: params; offsets gathered from redO partials ----
  bool ok = true;
  float offy = 0.f, offx = 0.f;
  int pixl = t & 15, kk = t >> 4;
  bool active = (t < 144);
  if (active) {
    int ocy = 2 * kk, ocx = ocy + 1;
    int ogy = ocy >> 4, ogx = ocx >> 4;
    int lny = ((pixl >> 2) << 4) | (ocy & 15);
    int lnx = ((pixl >> 2) << 4) | (ocx & 15);
    int jj = pixl & 3;
    offy = redO[(ogy * 64 + lny) * 4 + jj] + redO[((ogy + 2) * 64 + lny) * 4 + jj] + offb[ocy];
    offx = redO[(ogx * 64 + lnx) * 4 + jj] + redO[((ogx + 2) * 64 + lnx) * 4 + jj] + offb[ocx];
    int xx = x0 + pixl;
    float sy = (float)(y + (kk / 3) - 1) + offy;
    float sx = (float)(xx + (kk % 3) - 1) + offx;
    float fy = floorf(sy), fx = floorf(sx);
    float wy = sy - fy, wx = sx - fx;
    int iy = (int)fy, ix = (int)fx;
    float w[4];
    int rc[4];
#pragma unroll
    for (int j = 0; j < 4; ++j) {
      int dy = j >> 1, dx = j & 1;
      int yc = iy + dy, xc = ix + dx;
      bool v = ((unsigned)yc < 128u) && ((unsigned)xc < 128u);
      int ycc = min(max(yc, 0), 127), xcc = min(max(xc, 0), 127);
      float wgt = (dy ? wy : 1.f - wy) * (dx ? wx : 1.f - wx);
      w[j] = v ? wgt : 0.f;
      bool in_tile = (ycc >= ty) && (ycc <= ty + 4) && (xcc >= tx) && (xcc <= tx + 19);
      ok = ok && ((w[j] == 0.f) || in_tile);
      int ry = min(max(ycc - ty, 0), 4);
      int rx = min(max(xcc - tx, 0), 19);
      rc[j] = ry * 20 + rx;
    }
    cwb[t] = make_uint2(pack2(w[0], w[1]), pack2(w[2], w[3]));
    rel4[t] = make_uchar4((unsigned char)rc[0], (unsigned char)rc[1],
                          (unsigned char)rc[2], (unsigned char)rc[3]);
    // zero own k-pad strip in sAb (c = 64..67)
    *(uint2*)(sAb + pixl * ROWS + kk * 68 + 64) = make_uint2(0u, 0u);
  }
  {
    unsigned long long m = __ballot(ok);
    if (lane == 0) wOK[wv] = (m == ~0ull) ? 1 : 0;
  }
  __syncthreads();

  bool fast = wOK[0] && wOK[1] && wOK[2] && wOK[3];

  // ---- Phase 3: sampling, 288 half-job slots (R14-proven) ----
  if (fast) {
    auto do_slot = [&](int slot) {
      int job = slot >> 1, hf = slot & 1;
      int jp = job & 15, jk = job >> 4;
      int bg = hf * 4;
      uint2 wp = cwb[job];
      float w0 = bfl((unsigned short)(wp.x & 0xffffu));
      float w1_ = bfl((unsigned short)(wp.x >> 16));
      float w2_ = bfl((unsigned short)(wp.y & 0xffffu));
      float w3_ = bfl((unsigned short)(wp.y >> 16));
      uchar4 rl = rel4[job];
      int r0 = rl.x, r1 = rl.y, r2 = rl.z, r3 = rl.w;
      unsigned short* wr = sAb + jp * ROWS + jk * 68 + hf * 32;
#pragma unroll
      for (int gg = 0; gg < 4; ++gg) {
        int g = bg + gg;
        bf16x8 v0 = *(const bf16x8*)(tileTb + r0 * TSTR + ((g ^ (r0 & 7)) << 3));
        bf16x8 v1 = *(const bf16x8*)(tileTb + r1 * TSTR + ((g ^ (r1 & 7)) << 3));
        bf16x8 v2 = *(const bf16x8*)(tileTb + r2 * TSTR + ((g ^ (r2 & 7)) << 3));
        bf16x8 v3 = *(const bf16x8*)(tileTb + r3 * TSTR + ((g ^ (r3 & 7)) << 3));
        unsigned dws[4];
#pragma unroll
        for (int e = 0; e < 8; e += 2) {
          float lo = w0 * bfl((unsigned short)v0[e]) + w1_ * bfl((unsigned short)v1[e]) +
                     w2_ * bfl((unsigned short)v2[e]) + w3_ * bfl((unsigned short)v3[e]);
          float hi = w0 * bfl((unsigned short)v0[e + 1]) + w1_ * bfl((unsigned short)v1[e + 1]) +
                     w2_ * bfl((unsigned short)v2[e + 1]) + w3_ * bfl((unsigned short)v3[e + 1]);
          dws[e >> 1] = pack2(lo, hi);
        }
        *(uint2*)(wr + gg * 8) = make_uint2(dws[0], dws[1]);
        *(uint2*)(wr + gg * 8 + 4) = make_uint2(dws[2], dws[3]);
      }
    };
    do_slot(t);
    if ((t & 7) == 0) do_slot(256 + (t >> 3));
  } else {
    if (active) {
      // slow path: corners from register offy/offx, sample NHWC p globally
      int xx = x0 + pixl;
      float sy = (float)(y + (kk / 3) - 1) + offy;
      float sx = (float)(xx + (kk % 3) - 1) + offx;
      float fy = floorf(sy), fx = floorf(sx);
      float wy = sy - fy, wx = sx - fx;
      int iy = (int)fy, ix = (int)fx;
      float wj[4];
      const unsigned short* pc[4];
#pragma unroll
      for (int j = 0; j < 4; ++j) {
        int dy = j >> 1, dx = j & 1;
        int yc = iy + dy, xc = ix + dx;
        bool v = ((unsigned)yc < 128u) && ((unsigned)xc < 128u);
        int ycc = min(max(yc, 0), 127), xcc = min(max(xc, 0), 127);
        wj[j] = v ? (dy ? wy : 1.f - wy) * (dx ? wx : 1.f - wx) : 0.f;
        pc[j] = pB + ((size_t)(ycc * W_ + xcc)) * 64;
      }
      unsigned short* wr = sAb + pixl * ROWS + kk * 68;
#pragma unroll 4
      for (int c = 0; c < 64; ++c) {
        float v = wj[0] * bfl(pc[0][c]) + wj[1] * bfl(pc[1][c]) +
                  wj[2] * bfl(pc[2][c]) + wj[3] * bfl(pc[3][c]);
        wr[c] = f2bf(v);
      }
    }
  }
  __syncthreads();

  // ---- Phase 4: deform GEMM (19 slots, proven pairing + D layout) ----
  f32x4 acc;
  {
    float d = db[o_me];
    acc = (f32x4){d, d, d, d};
  }
  const unsigned short* arow = sAb + l15 * ROWS + (lp << 3);
  const bf16x8* wfp = (const bf16x8*)wf2;
#pragma unroll
  for (int s = 0; s < KSLOTS; ++s) {
    bf16x8 a = *(const bf16x8*)(arow + s * 32);
    bf16x8 bw = wfp[(s * 4 + wv) * 64 + lane];
    acc = __builtin_amdgcn_mfma_f32_16x16x32_bf16(a, bw, acc, 0, 0, 0);
  }

#pragma unroll
  for (int j = 0; j < 4; ++j) {
    rTb[(px0 + j) * 72 + o_me] = f2bf(acc[j]);
  }
  __syncthreads();

  // ---- conv1 + BN + ReLU + residual ----
  f32x4 acc1;
  {
    float bb = b1f[o_me];
    acc1 = (f32x4){bb, bb, bb, bb};
  }
  const unsigned short* arow1 = rTb + l15 * 72 + (lp << 3);
  const bf16x8* w1f8 = (const bf16x8*)w1p;
#pragma unroll
  for (int s = 0; s < 2; ++s) {
    bf16x8 a = *(const bf16x8*)(arow1 + s * 32);
    bf16x8 bw = w1f8[(s * 4 + wv) * 64 + lane];
    acc1 = __builtin_amdgcn_mfma_f32_16x16x32_bf16(a, bw, acc1, 0, 0, 0);
  }
  float h0 = fmaxf(acc1[0], 0.f) + xv.x;
  float h1 = fmaxf(acc1[1], 0.f) + xv.y;
  float h2 = fmaxf(acc1[2], 0.f) + xv.z;
  float h3 = fmaxf(acc1[3], 0.f) + xv.w;
  hTb[(px0 + 0) * 72 + o_me] = f2bf(h0);
  hTb[(px0 + 1) * 72 + o_me] = f2bf(h1);
  hTb[(px0 + 2) * 72 + o_me] = f2bf(h2);
  hTb[(px0 + 3) * 72 + o_me] = f2bf(h3);
  __syncthreads();

  // ---- conv2 ----
  f32x4 acc2;
  {
    float bo = b2[o_me];
    acc2 = (f32x4){bo, bo, bo, bo};
  }
  const unsigned short* arow2 = hTb + l15 * 72 + (lp << 3);
  const bf16x8* w2f8 = (const bf16x8*)w2p;
#pragma unroll
  for (int s = 0; s < 2; ++s) {
    bf16x8 a = *(const bf16x8*)(arow2 + s * 32);
    bf16x8 bw = w2f8[(s * 4 + wv) * 64 + lane];
    acc2 = __builtin_amdgcn_mfma_f32_16x16x32_bf16(a, bw, acc2, 0, 0, 0);
  }
  *(float4*)(out + (size_t)(b * C_ + o_me) * HW_ + yx0 + px0) =
      make_float4(acc2[0], acc2[1], acc2[2], acc2[3]);
}

extern "C" void kernel_launch(void* const* d_in, const int* in_sizes, int n_in,
                              void* d_out, int out_size, void* d_ws, size_t ws_size,
                              hipStream_t stream) {
  const float* x = (const float*)d_in[0];
  const float* offw = (const float*)d_in[1];
  const float* offb = (const float*)d_in[2];
  const float* dw = (const float*)d_in[3];
  const float* db = (const float*)d_in[4];
  const float* w1 = (const float*)d_in[5];
  const float* b1 = (const float*)d_in[6];
  const float* gamma = (const float*)d_in[7];
  const float* beta = (const float*)d_in[8];
  const float* rmean = (const float*)d_in[9];
  const float* rvar = (const float*)d_in[10];
  const float* w2 = (const float*)d_in[11];
  const float* b2 = (const float*)d_in[12];
  float* out = (float*)d_out;

  unsigned short* pbf = (unsigned short*)d_ws;             // 8388608 bf16 (NHWC)
  unsigned short* wf2 = pbf + 8388608;                     // 38912 bf16
  unsigned short* offwp = wf2 + 38912;                     // 18432 bf16
  unsigned short* w1p = offwp + 18432;                     // 4096 bf16
  unsigned short* w2p = w1p + 4096;                        // 4096 bf16
  float* b1f = (float*)(w2p + 4096);                       // 64 f

  prep_kernel<<<257, 256, 0, stream>>>(dw, offw, w1, b1, gamma, beta, rmean,
                                       rvar, w2, wf2, offwp, w1p, w2p, b1f);
  avgpool_kernel<<<2048, 256, 0, stream>>>(x, pbf);
  deform_kernel<<<8192, 256, 0, stream>>>(pbf, wf2, offwp, w1p, w2p, offb, db,
                                          b1f, b2, x, out);
}

// Round 16
// 115.004 us; speedup vs baseline: 1.0756x; 1.0756x over previous
//
#include <hip/hip_runtime.h>
#include <hip/hip_bf16.h>
#include <cstddef>

#define H_ 128
#define W_ 128
#define HW_ 16384
#define C_ 64
#define B_ 8
#define EPS_ 1e-5f

#define KSLOTS 19   // deform GEMM k-slots, k = kk*68 + c (c<64 data, 64..67 pad)
#define ROWS 616    // sAb row stride (shorts); 308 dwords, 77 ≡ 5 mod 8 (clean)
#define TSTR 64     // tile row stride (shorts) = 32 dwords ≡ 0 mod 32 banks
#define OTSTR 64    // offconv tile row stride (shorts)

typedef __attribute__((ext_vector_type(8))) short bf16x8;
typedef __attribute__((ext_vector_type(4))) float f32x4;

__device__ __forceinline__ unsigned short f2bf(float f) {
  __hip_bfloat16 h = __float2bfloat16(f);
  unsigned short u;
  __builtin_memcpy(&u, &h, 2);
  return u;
}
__device__ __forceinline__ unsigned pack2(float lo, float hi) {
  return (unsigned)f2bf(lo) | ((unsigned)f2bf(hi) << 16);
}
__device__ __forceinline__ float bfl(unsigned short v) {
  return __uint_as_float(((unsigned)v) << 16);
}

// ---------------- prep: pack ALL GEMM weights (proven) ----------------------
__global__ __launch_bounds__(256) void prep_kernel(
    const float* __restrict__ dw, const float* __restrict__ offw,
    const float* __restrict__ w1, const float* __restrict__ b1,
    const float* __restrict__ gamma, const float* __restrict__ beta,
    const float* __restrict__ rmean, const float* __restrict__ rvar,
    const float* __restrict__ w2,
    unsigned short* __restrict__ wf2, unsigned short* __restrict__ offwp,
    unsigned short* __restrict__ w1p, unsigned short* __restrict__ w2p,
    float* __restrict__ b1f) {
  int i = blockIdx.x * 256 + threadIdx.x;
  if (i < 38912) {  // deform: 19 sg * 4 og * 64 l * 8 j, k = kk*68 + c
    int j = i & 7, l = (i >> 3) & 63, og = (i >> 9) & 3, sg = i >> 11;
    int o = og * 16 + (l & 15);
    int k = sg * 32 + ((l >> 4) << 3) + j;
    int kk = k / 68, c = k - kk * 68;
    float v = (c < 64) ? dw[o * 576 + c * 9 + kk] : 0.f;
    wf2[i] = f2bf(v);
  } else if (i < 38912 + 18432) {  // offconv: 18 slot * 2 og * 64 l * 8 j
    int j2 = i - 38912;
    int j = j2 & 7, l = (j2 >> 3) & 63, og = (j2 >> 9) & 1, slot = j2 >> 10;
    int kk = slot >> 1, s = slot & 1;
    int oc = og * 16 + (l & 15);
    int c = s * 32 + ((l >> 4) << 3) + j;
    float v = (oc < 18) ? offw[oc * 576 + c * 9 + kk] : 0.f;
    offwp[j2] = f2bf(v);
  } else if (i < 38912 + 18432 + 4096) {
    int j2 = i - 38912 - 18432;
    int j = j2 & 7, l = (j2 >> 3) & 63, og = (j2 >> 9) & 3, sg = j2 >> 11;
    int o = og * 16 + (l & 15);
    int c = sg * 32 + ((l >> 4) << 3) + j;
    float inv = gamma[o] * rsqrtf(rvar[o] + EPS_);
    w1p[j2] = f2bf(w1[o * 64 + c] * inv);
  } else if (i < 38912 + 18432 + 8192) {
    int j2 = i - 38912 - 18432 - 4096;
    int j = j2 & 7, l = (j2 >> 3) & 63, og = (j2 >> 9) & 3, sg = j2 >> 11;
    int o = og * 16 + (l & 15);
    int c = sg * 32 + ((l >> 4) << 3) + j;
    w2p[j2] = f2bf(w2[o * 64 + c]);
  } else if (i < 38912 + 18432 + 8192 + 64) {
    int o = i - 38912 - 18432 - 8192;
    float inv = gamma[o] * rsqrtf(rvar[o] + EPS_);
    b1f[o] = b1[o] * inv + beta[o] - rmean[o] * inv;
  }
}

// ---------------- avg pool 3x3 -> NHWC bf16 (R14, proven) ----------------
__global__ __launch_bounds__(256) void avgpool_kernel(const float* __restrict__ xin,
                                                      unsigned short* __restrict__ pbf) {
  __shared__ __align__(16) unsigned short pool[64 * 72];
  int t = threadIdx.x;
  int c = t & 63, wvp = t >> 6;
  int blk = blockIdx.x;
  int half = blk & 1;
  int row = blk >> 1;
  int b = row >> 7, y = row & 127;
  int xb = half * 64 + wvp * 16;
  const float* q = xin + (size_t)(b * C_ + c) * HW_;

  float ver[16];
#pragma unroll
  for (int i = 0; i < 16; ++i) ver[i] = 0.f;
#pragma unroll
  for (int dy = -1; dy <= 1; ++dy) {
    int yy = y + dy;
    if ((unsigned)yy < 128u) {
      const float* r = q + yy * W_;
      float m[18];
      m[0] = (xb > 0) ? r[xb - 1] : 0.f;
      float4 v0 = *(const float4*)(r + xb);
      float4 v1 = *(const float4*)(r + xb + 4);
      float4 v2 = *(const float4*)(r + xb + 8);
      float4 v3 = *(const float4*)(r + xb + 12);
      m[1] = v0.x; m[2] = v0.y; m[3] = v0.z; m[4] = v0.w;
      m[5] = v1.x; m[6] = v1.y; m[7] = v1.z; m[8] = v1.w;
      m[9] = v2.x; m[10] = v2.y; m[11] = v2.z; m[12] = v2.w;
      m[13] = v3.x; m[14] = v3.y; m[15] = v3.z; m[16] = v3.w;
      m[17] = (xb < 112) ? r[xb + 16] : 0.f;
#pragma unroll
      for (int i = 0; i < 16; ++i) ver[i] += m[i] + m[i + 1] + m[i + 2];
    }
  }
  int pxb = wvp * 16;
#pragma unroll
  for (int i = 0; i < 16; ++i) {
    int px = pxb + i;
    int cg = c >> 3;
    pool[px * 72 + ((cg ^ (px & 7)) << 3) + (c & 7)] = f2bf(ver[i] * (1.f / 9.f));
  }
  __syncthreads();

  size_t base = ((size_t)(b * HW_) + y * W_ + half * 64) * 64;
#pragma unroll
  for (int k = 0; k < 2; ++k) {
    int ch = k * 256 + t;
    int px = ch >> 3, g = ch & 7;
    uint2 v = *(const uint2*)(pool + px * 72 + ((g ^ (px & 7)) << 3));
    uint2 v2 = *(const uint2*)(pool + px * 72 + ((g ^ (px & 7)) << 3) + 4);
    *(uint4*)(pbf + base + px * 64 + g * 8) = make_uint4(v.x, v.y, v2.x, v2.y);
  }
}

// ---------------- offset conv via MFMA (stride-64 swizzled tile) ------------
__global__ __launch_bounds__(256, 4) void offconv_kernel(
    const unsigned short* __restrict__ pbf, const unsigned short* __restrict__ offwp,
    const float* __restrict__ offb, float* __restrict__ off) {
  __shared__ __align__(16) unsigned short tile[198 * OTSTR];  // 25344 B
  __shared__ float offT[18 * 64];                             // 4608 B
  int t = threadIdx.x;
  int lane = t & 63, wv = t >> 6;
  int l15 = lane & 15, lp = lane >> 4;
  int blk = blockIdx.x;
  int half = blk & 1;
  int row = blk >> 1;
  int b = row >> 7, y = row & 127;
  int x0 = half * 64;

  // stage: 198 rows x 8 granules = 1584 chunks of 16B from NHWC pbf
#pragma unroll
  for (int it = 0; it < 7; ++it) {
    int ch = it * 256 + t;
    if (ch < 1584) {
      int rc = ch >> 3, g = ch & 7;
      int r = rc / 66, cx = rc - r * 66;
      int iy = y - 1 + r, ix = x0 - 1 + cx;
      uint4 v = make_uint4(0u, 0u, 0u, 0u);
      if (((unsigned)iy < 128u) && ((unsigned)ix < 128u)) {
        v = *(const uint4*)(pbf + ((size_t)(b * HW_) + iy * W_ + ix) * 64 + g * 8);
      }
      *(uint4*)(tile + rc * OTSTR + ((g ^ (rc & 7)) << 3)) = v;
    }
  }
  __syncthreads();

  int og = wv & 1;
  int oc = og * 16 + l15;
  float bo = offb[min(oc, 17)];
  const bf16x8* ofp = (const bf16x8*)offwp;
#pragma unroll
  for (int pti = 0; pti < 2; ++pti) {
    int pt = (wv >> 1) + pti * 2;
    f32x4 aco = (f32x4){bo, bo, bo, bo};
#pragma unroll
    for (int kk = 0; kk < 9; ++kk) {
      int rowb = (kk / 3) * 66 + (kk % 3) + pt * 16 + l15;
#pragma unroll
      for (int s = 0; s < 2; ++s) {
        int ga = s * 4 + lp;
        bf16x8 a = *(const bf16x8*)(tile + rowb * OTSTR + ((ga ^ (rowb & 7)) << 3));
        bf16x8 bw = ofp[((kk * 2 + s) * 2 + og) * 64 + lane];
        aco = __builtin_amdgcn_mfma_f32_16x16x32_bf16(a, bw, aco, 0, 0, 0);
      }
    }
    if (oc < 18) {
#pragma unroll
      for (int j = 0; j < 4; ++j) offT[oc * 64 + pt * 16 + lp * 4 + j] = aco[j];
    }
  }
  __syncthreads();

#pragma unroll
  for (int it = 0; it < 5; ++it) {
    int idx = it * 256 + t;
    if (idx < 1152) {
      int oc2 = idx >> 6, px = idx & 63;
      off[(size_t)(b * 18 + oc2) * HW_ + y * W_ + x0 + px] = offT[idx];
    }
  }
}

// ---------------- deform (R14 structure, stride-64 swizzled tile) -----------
__global__ __launch_bounds__(256, 4) void deform_kernel(
    const unsigned short* __restrict__ pbf, const float* __restrict__ off,
    const unsigned short* __restrict__ wf2, const unsigned short* __restrict__ w1p,
    const unsigned short* __restrict__ w2p, const float* __restrict__ db,
    const float* __restrict__ b1f, const float* __restrict__ b2,
    const float* __restrict__ xin, float* __restrict__ out) {
  __shared__ __align__(16) unsigned short tileTb[100 * TSTR];  // 12800 B
  __shared__ __align__(16) unsigned short sAb[16 * ROWS];      // 19712 B
  __shared__ __align__(16) unsigned short rTb[16 * 72];        // 2304 B
  __shared__ __align__(16) unsigned short hTb[16 * 72];        // 2304 B
  __shared__ uint2 cwb[144];                                   // 1152 B
  __shared__ uchar4 rel4[144];                                 // 576 B
  __shared__ int wOK[4];
  int t = threadIdx.x;
  int lane = t & 63, wv = t >> 6;
  int l15 = lane & 15, lp = lane >> 4;
  int pix0 = blockIdx.x * 16;
  int b = pix0 >> 14;
  int yx0 = pix0 & 16383;
  int y = yx0 >> 7, x0 = yx0 & 127;
  int ty = min(max(y - 2, 0), 123);
  int tx = min(max(x0 - 2, 0), 108);
  const unsigned short* pB = pbf + (size_t)(b * HW_) * 64;

  int o_me = wv * 16 + l15;
  int px0 = lp * 4;
  const float4 xv = *(const float4*)(xin + (size_t)(b * C_ + o_me) * HW_ + yx0 + px0);

  // ---- params: thread t<144 -> job (pixl = t&15, kk = t>>4) ----
  bool ok = true;
  int pixl = t & 15, kk = t >> 4;
  bool active = (t < 144);
  if (active) {
    int xx = x0 + pixl;
    const float* ob = off + (size_t)(b * 18 + kk * 2) * HW_ + y * W_ + xx;
    float offy = ob[0];
    float offx = ob[HW_];
    float sy = (float)(y + (kk / 3) - 1) + offy;
    float sx = (float)(xx + (kk % 3) - 1) + offx;
    float fy = floorf(sy), fx = floorf(sx);
    float wy = sy - fy, wx = sx - fx;
    int iy = (int)fy, ix = (int)fx;
    float w[4];
    int rc[4];
#pragma unroll
    for (int j = 0; j < 4; ++j) {
      int dy = j >> 1, dx = j & 1;
      int yc = iy + dy, xc = ix + dx;
      bool v = ((unsigned)yc < 128u) && ((unsigned)xc < 128u);
      int ycc = min(max(yc, 0), 127), xcc = min(max(xc, 0), 127);
      float wgt = (dy ? wy : 1.f - wy) * (dx ? wx : 1.f - wx);
      w[j] = v ? wgt : 0.f;
      bool in_tile = (ycc >= ty) && (ycc <= ty + 4) && (xcc >= tx) && (xcc <= tx + 19);
      ok = ok && ((w[j] == 0.f) || in_tile);
      int ry = min(max(ycc - ty, 0), 4);
      int rx = min(max(xcc - tx, 0), 19);
      rc[j] = ry * 20 + rx;
    }
    cwb[t] = make_uint2(pack2(w[0], w[1]), pack2(w[2], w[3]));
    rel4[t] = make_uchar4((unsigned char)rc[0], (unsigned char)rc[1],
                          (unsigned char)rc[2], (unsigned char)rc[3]);
    // zero own k-pad strip in sAb (c = 64..67)
    *(uint2*)(sAb + pixl * ROWS + kk * 68 + 64) = make_uint2(0u, 0u);
  }
  {
    unsigned long long m = __ballot(ok);
    if (lane == 0) wOK[wv] = (m == ~0ull) ? 1 : 0;
  }

  // ---- stage tile: 100 rows x 8 granules = 800 chunks of 16B (NHWC copy) ----
#pragma unroll
  for (int it = 0; it < 3; ++it) {
    int ch = it * 256 + t;  // 0..767
    int rc = ch >> 3, g = ch & 7;
    int r = rc / 20, cx = rc - r * 20;
    uint4 v = *(const uint4*)(pB + ((size_t)((ty + r) * W_ + tx + cx)) * 64 + g * 8);
    *(uint4*)(tileTb + rc * TSTR + ((g ^ (rc & 7)) << 3)) = v;
  }
  if (t < 32) {
    int ch = 768 + t;
    int rc = ch >> 3, g = ch & 7;
    int r = rc / 20, cx = rc - r * 20;
    uint4 v = *(const uint4*)(pB + ((size_t)((ty + r) * W_ + tx + cx)) * 64 + g * 8);
    *(uint4*)(tileTb + rc * TSTR + ((g ^ (rc & 7)) << 3)) = v;
  }
  __syncthreads();

  bool fast = wOK[0] && wOK[1] && wOK[2] && wOK[3];

  // ---- sampling: 288 half-job slots over 256 threads (R14 distribution) ----
  if (fast) {
    auto do_slot = [&](int slot) {
      int job = slot >> 1, hf = slot & 1;
      int jp = job & 15, jk = job >> 4;
      int bg = hf * 4;
      uint2 wp = cwb[job];
      float w0 = bfl((unsigned short)(wp.x & 0xffffu));
      float w1_ = bfl((unsigned short)(wp.x >> 16));
      float w2_ = bfl((unsigned short)(wp.y & 0xffffu));
      float w3_ = bfl((unsigned short)(wp.y >> 16));
      uchar4 rl = rel4[job];
      int r0 = rl.x, r1 = rl.y, r2 = rl.z, r3 = rl.w;
      unsigned short* wr = sAb + jp * ROWS + jk * 68 + hf * 32;
#pragma unroll
      for (int gg = 0; gg < 4; ++gg) {
        int g = bg + gg;
        bf16x8 v0 = *(const bf16x8*)(tileTb + r0 * TSTR + ((g ^ (r0 & 7)) << 3));
        bf16x8 v1 = *(const bf16x8*)(tileTb + r1 * TSTR + ((g ^ (r1 & 7)) << 3));
        bf16x8 v2 = *(const bf16x8*)(tileTb + r2 * TSTR + ((g ^ (r2 & 7)) << 3));
        bf16x8 v3 = *(const bf16x8*)(tileTb + r3 * TSTR + ((g ^ (r3 & 7)) << 3));
        unsigned dws[4];
#pragma unroll
        for (int e = 0; e < 8; e += 2) {
          float lo = w0 * bfl((unsigned short)v0[e]) + w1_ * bfl((unsigned short)v1[e]) +
                     w2_ * bfl((unsigned short)v2[e]) + w3_ * bfl((unsigned short)v3[e]);
          float hi = w0 * bfl((unsigned short)v0[e + 1]) + w1_ * bfl((unsigned short)v1[e + 1]) +
                     w2_ * bfl((unsigned short)v2[e + 1]) + w3_ * bfl((unsigned short)v3[e + 1]);
          dws[e >> 1] = pack2(lo, hi);
        }
        *(uint2*)(wr + gg * 8) = make_uint2(dws[0], dws[1]);
        *(uint2*)(wr + gg * 8 + 4) = make_uint2(dws[2], dws[3]);
      }
    };
    do_slot(t);
    if ((t & 7) == 0) do_slot(256 + (t >> 3));
  } else {
    if (active) {
      // slow path: recompute corners, sample NHWC bf16 p globally
      int xx = x0 + pixl;
      const float* ob = off + (size_t)(b * 18 + kk * 2) * HW_ + y * W_ + xx;
      float offy = ob[0];
      float offx = ob[HW_];
      float sy = (float)(y + (kk / 3) - 1) + offy;
      float sx = (float)(xx + (kk % 3) - 1) + offx;
      float fy = floorf(sy), fx = floorf(sx);
      float wy = sy - fy, wx = sx - fx;
      int iy = (int)fy, ix = (int)fx;
      float wj[4];
      const unsigned short* pc[4];
#pragma unroll
      for (int j = 0; j < 4; ++j) {
        int dy = j >> 1, dx = j & 1;
        int yc = iy + dy, xc = ix + dx;
        bool v = ((unsigned)yc < 128u) && ((unsigned)xc < 128u);
        int ycc = min(max(yc, 0), 127), xcc = min(max(xc, 0), 127);
        wj[j] = v ? (dy ? wy : 1.f - wy) * (dx ? wx : 1.f - wx) : 0.f;
        pc[j] = pB + ((size_t)(ycc * W_ + xcc)) * 64;
      }
      unsigned short* wr = sAb + pixl * ROWS + kk * 68;
#pragma unroll 4
      for (int c = 0; c < 64; ++c) {
        float v = wj[0] * bfl(pc[0][c]) + wj[1] * bfl(pc[1][c]) +
                  wj[2] * bfl(pc[2][c]) + wj[3] * bfl(pc[3][c]);
        wr[c] = f2bf(v);
      }
    }
  }
  __syncthreads();

  // ---- deform GEMM: 19 slots (proven A/B pairing + D layout) ----
  f32x4 acc;
  {
    float d = db[o_me];
    acc = (f32x4){d, d, d, d};
  }
  const unsigned short* arow = sAb + l15 * ROWS + (lp << 3);
  const bf16x8* wfp = (const bf16x8*)wf2;
#pragma unroll
  for (int s = 0; s < KSLOTS; ++s) {
    bf16x8 a = *(const bf16x8*)(arow + s * 32);
    bf16x8 bw = wfp[(s * 4 + wv) * 64 + lane];
    acc = __builtin_amdgcn_mfma_f32_16x16x32_bf16(a, bw, acc, 0, 0, 0);
  }

#pragma unroll
  for (int j = 0; j < 4; ++j) {
    rTb[(px0 + j) * 72 + o_me] = f2bf(acc[j]);
  }
  __syncthreads();

  // ---- conv1 + BN + ReLU + residual ----
  f32x4 acc1;
  {
    float bb = b1f[o_me];
    acc1 = (f32x4){bb, bb, bb, bb};
  }
  const unsigned short* arow1 = rTb + l15 * 72 + (lp << 3);
  const bf16x8* w1f8 = (const bf16x8*)w1p;
#pragma unroll
  for (int s = 0; s < 2; ++s) {
    bf16x8 a = *(const bf16x8*)(arow1 + s * 32);
    bf16x8 bw = w1f8[(s * 4 + wv) * 64 + lane];
    acc1 = __builtin_amdgcn_mfma_f32_16x16x32_bf16(a, bw, acc1, 0, 0, 0);
  }
  float h0 = fmaxf(acc1[0], 0.f) + xv.x;
  float h1 = fmaxf(acc1[1], 0.f) + xv.y;
  float h2 = fmaxf(acc1[2], 0.f) + xv.z;
  float h3 = fmaxf(acc1[3], 0.f) + xv.w;
  hTb[(px0 + 0) * 72 + o_me] = f2bf(h0);
  hTb[(px0 + 1) * 72 + o_me] = f2bf(h1);
  hTb[(px0 + 2) * 72 + o_me] = f2bf(h2);
  hTb[(px0 + 3) * 72 + o_me] = f2bf(h3);
  __syncthreads();

  // ---- conv2 ----
  f32x4 acc2;
  {
    float bo = b2[o_me];
    acc2 = (f32x4){bo, bo, bo, bo};
  }
  const unsigned short* arow2 = hTb + l15 * 72 + (lp << 3);
  const bf16x8* w2f8 = (const bf16x8*)w2p;
#pragma unroll
  for (int s = 0; s < 2; ++s) {
    bf16x8 a = *(const bf16x8*)(arow2 + s * 32);
    bf16x8 bw = w2f8[(s * 4 + wv) * 64 + lane];
    acc2 = __builtin_amdgcn_mfma_f32_16x16x32_bf16(a, bw, acc2, 0, 0, 0);
  }
  *(float4*)(out + (size_t)(b * C_ + o_me) * HW_ + yx0 + px0) =
      make_float4(acc2[0], acc2[1], acc2[2], acc2[3]);
}

extern "C" void kernel_launch(void* const* d_in, const int* in_sizes, int n_in,
                              void* d_out, int out_size, void* d_ws, size_t ws_size,
                              hipStream_t stream) {
  const float* x = (const float*)d_in[0];
  const float* offw = (const float*)d_in[1];
  const float* offb = (const float*)d_in[2];
  const float* dw = (const float*)d_in[3];
  const float* db = (const float*)d_in[4];
  const float* w1 = (const float*)d_in[5];
  const float* b1 = (const float*)d_in[6];
  const float* gamma = (const float*)d_in[7];
  const float* beta = (const float*)d_in[8];
  const float* rmean = (const float*)d_in[9];
  const float* rvar = (const float*)d_in[10];
  const float* w2 = (const float*)d_in[11];
  const float* b2 = (const float*)d_in[12];
  float* out = (float*)d_out;

  unsigned short* pbf = (unsigned short*)d_ws;      // 8388608 bf16 (NHWC)
  float* off = (float*)(pbf + 8388608);             // 2359296 f
  unsigned short* wf2 = (unsigned short*)(off + 2359296);  // 38912 bf16
  unsigned short* offwp = wf2 + 38912;              // 18432 bf16
  unsigned short* w1p = offwp + 18432;              // 4096 bf16
  unsigned short* w2p = w1p + 4096;                 // 4096 bf16
  float* b1f = (float*)(w2p + 4096);                // 64 f

  prep_kernel<<<257, 256, 0, stream>>>(dw, offw, w1, b1, gamma, beta, rmean,
                                       rvar, w2, wf2, offwp, w1p, w2p, b1f);
  avgpool_kernel<<<2048, 256, 0, stream>>>(x, pbf);
  offconv_kernel<<<2048, 256, 0, stream>>>(pbf, offwp, offb, off);
  deform_kernel<<<8192, 256, 0, stream>>>(pbf, off, wf2, w1p, w2p, db, b1f, b2,
                                          x, out);
}

// Round 17
// 109.190 us; speedup vs baseline: 1.1329x; 1.0532x over previous
//
#include <hip/hip_runtime.h>
#include <hip/hip_bf16.h>
#include <cstddef>

#define H_ 128
#define W_ 128
#define HW_ 16384
#define C_ 64
#define B_ 8
#define EPS_ 1e-5f

#define KSLOTS 19   // deform GEMM k-slots, k = kk*68 + c (c<64 data, 64..67 pad)
#define ROWS 616    // sAb row stride (shorts); 308 dwords, ok mod 8
#define TSTR 64     // tile row stride (shorts) = 32 dwords ≡ 0 mod 32 banks
#define OTSTR 64    // offconv tile row stride (shorts)

typedef __attribute__((ext_vector_type(8))) short bf16x8;
typedef __attribute__((ext_vector_type(4))) float f32x4;
typedef __attribute__((ext_vector_type(2))) float f32x2;

__device__ __forceinline__ unsigned short f2bf(float f) {
  __hip_bfloat16 h = __float2bfloat16(f);
  unsigned short u;
  __builtin_memcpy(&u, &h, 2);
  return u;
}
__device__ __forceinline__ unsigned pack2(float lo, float hi) {
  return (unsigned)f2bf(lo) | ((unsigned)f2bf(hi) << 16);
}
__device__ __forceinline__ float bfl(unsigned short v) {
  return __uint_as_float(((unsigned)v) << 16);
}

// ---------------- prep: pack ALL GEMM weights (proven) ----------------------
__global__ __launch_bounds__(256) void prep_kernel(
    const float* __restrict__ dw, const float* __restrict__ offw,
    const float* __restrict__ w1, const float* __restrict__ b1,
    const float* __restrict__ gamma, const float* __restrict__ beta,
    const float* __restrict__ rmean, const float* __restrict__ rvar,
    const float* __restrict__ w2,
    unsigned short* __restrict__ wf2, unsigned short* __restrict__ offwp,
    unsigned short* __restrict__ w1p, unsigned short* __restrict__ w2p,
    float* __restrict__ b1f) {
  int i = blockIdx.x * 256 + threadIdx.x;
  if (i < 38912) {  // deform: 19 sg * 4 og * 64 l * 8 j, k = kk*68 + c
    int j = i & 7, l = (i >> 3) & 63, og = (i >> 9) & 3, sg = i >> 11;
    int o = og * 16 + (l & 15);
    int k = sg * 32 + ((l >> 4) << 3) + j;
    int kk = k / 68, c = k - kk * 68;
    float v = (c < 64) ? dw[o * 576 + c * 9 + kk] : 0.f;
    wf2[i] = f2bf(v);
  } else if (i < 38912 + 18432) {  // offconv: 18 slot * 2 og * 64 l * 8 j
    int j2 = i - 38912;
    int j = j2 & 7, l = (j2 >> 3) & 63, og = (j2 >> 9) & 1, slot = j2 >> 10;
    int kk = slot >> 1, s = slot & 1;
    int oc = og * 16 + (l & 15);
    int c = s * 32 + ((l >> 4) << 3) + j;
    float v = (oc < 18) ? offw[oc * 576 + c * 9 + kk] : 0.f;
    offwp[j2] = f2bf(v);
  } else if (i < 38912 + 18432 + 4096) {
    int j2 = i - 38912 - 18432;
    int j = j2 & 7, l = (j2 >> 3) & 63, og = (j2 >> 9) & 3, sg = j2 >> 11;
    int o = og * 16 + (l & 15);
    int c = sg * 32 + ((l >> 4) << 3) + j;
    float inv = gamma[o] * rsqrtf(rvar[o] + EPS_);
    w1p[j2] = f2bf(w1[o * 64 + c] * inv);
  } else if (i < 38912 + 18432 + 8192) {
    int j2 = i - 38912 - 18432 - 4096;
    int j = j2 & 7, l = (j2 >> 3) & 63, og = (j2 >> 9) & 3, sg = j2 >> 11;
    int o = og * 16 + (l & 15);
    int c = sg * 32 + ((l >> 4) << 3) + j;
    w2p[j2] = f2bf(w2[o * 64 + c]);
  } else if (i < 38912 + 18432 + 8192 + 64) {
    int o = i - 38912 - 18432 - 8192;
    float inv = gamma[o] * rsqrtf(rvar[o] + EPS_);
    b1f[o] = b1[o] * inv + beta[o] - rmean[o] * inv;
  }
}

// ---------------- avg pool 3x3 -> NHWC bf16 (R14, proven) ----------------
__global__ __launch_bounds__(256) void avgpool_kernel(const float* __restrict__ xin,
                                                      unsigned short* __restrict__ pbf) {
  __shared__ __align__(16) unsigned short pool[64 * 72];
  int t = threadIdx.x;
  int c = t & 63, wvp = t >> 6;
  int blk = blockIdx.x;
  int half = blk & 1;
  int row = blk >> 1;
  int b = row >> 7, y = row & 127;
  int xb = half * 64 + wvp * 16;
  const float* q = xin + (size_t)(b * C_ + c) * HW_;

  float ver[16];
#pragma unroll
  for (int i = 0; i < 16; ++i) ver[i] = 0.f;
#pragma unroll
  for (int dy = -1; dy <= 1; ++dy) {
    int yy = y + dy;
    if ((unsigned)yy < 128u) {
      const float* r = q + yy * W_;
      float m[18];
      m[0] = (xb > 0) ? r[xb - 1] : 0.f;
      float4 v0 = *(const float4*)(r + xb);
      float4 v1 = *(const float4*)(r + xb + 4);
      float4 v2 = *(const float4*)(r + xb + 8);
      float4 v3 = *(const float4*)(r + xb + 12);
      m[1] = v0.x; m[2] = v0.y; m[3] = v0.z; m[4] = v0.w;
      m[5] = v1.x; m[6] = v1.y; m[7] = v1.z; m[8] = v1.w;
      m[9] = v2.x; m[10] = v2.y; m[11] = v2.z; m[12] = v2.w;
      m[13] = v3.x; m[14] = v3.y; m[15] = v3.z; m[16] = v3.w;
      m[17] = (xb < 112) ? r[xb + 16] : 0.f;
#pragma unroll
      for (int i = 0; i < 16; ++i) ver[i] += m[i] + m[i + 1] + m[i + 2];
    }
  }
  int pxb = wvp * 16;
#pragma unroll
  for (int i = 0; i < 16; ++i) {
    int px = pxb + i;
    int cg = c >> 3;
    pool[px * 72 + ((cg ^ (px & 7)) << 3) + (c & 7)] = f2bf(ver[i] * (1.f / 9.f));
  }
  __syncthreads();

  size_t base = ((size_t)(b * HW_) + y * W_ + half * 64) * 64;
#pragma unroll
  for (int k = 0; k < 2; ++k) {
    int ch = k * 256 + t;
    int px = ch >> 3, g = ch & 7;
    uint2 v = *(const uint2*)(pool + px * 72 + ((g ^ (px & 7)) << 3));
    uint2 v2 = *(const uint2*)(pool + px * 72 + ((g ^ (px & 7)) << 3) + 4);
    *(uint4*)(pbf + base + px * 64 + g * 8) = make_uint4(v.x, v.y, v2.x, v2.y);
  }
}

// ---------------- offset conv via MFMA (stride-64 swizzled tile) ------------
__global__ __launch_bounds__(256, 4) void offconv_kernel(
    const unsigned short* __restrict__ pbf, const unsigned short* __restrict__ offwp,
    const float* __restrict__ offb, float* __restrict__ off) {
  __shared__ __align__(16) unsigned short tile[198 * OTSTR];  // 25344 B
  __shared__ float offT[18 * 64];                             // 4608 B
  int t = threadIdx.x;
  int lane = t & 63, wv = t >> 6;
  int l15 = lane & 15, lp = lane >> 4;
  int blk = blockIdx.x;
  int half = blk & 1;
  int row = blk >> 1;
  int b = row >> 7, y = row & 127;
  int x0 = half * 64;

#pragma unroll
  for (int it = 0; it < 7; ++it) {
    int ch = it * 256 + t;
    if (ch < 1584) {
      int rc = ch >> 3, g = ch & 7;
      int r = rc / 66, cx = rc - r * 66;
      int iy = y - 1 + r, ix = x0 - 1 + cx;
      uint4 v = make_uint4(0u, 0u, 0u, 0u);
      if (((unsigned)iy < 128u) && ((unsigned)ix < 128u)) {
        v = *(const uint4*)(pbf + ((size_t)(b * HW_) + iy * W_ + ix) * 64 + g * 8);
      }
      *(uint4*)(tile + rc * OTSTR + ((g ^ (rc & 7)) << 3)) = v;
    }
  }
  __syncthreads();

  int og = wv & 1;
  int oc = og * 16 + l15;
  float bo = offb[min(oc, 17)];
  const bf16x8* ofp = (const bf16x8*)offwp;
#pragma unroll
  for (int pti = 0; pti < 2; ++pti) {
    int pt = (wv >> 1) + pti * 2;
    f32x4 aco = (f32x4){bo, bo, bo, bo};
#pragma unroll
    for (int kk = 0; kk < 9; ++kk) {
      int rowb = (kk / 3) * 66 + (kk % 3) + pt * 16 + l15;
#pragma unroll
      for (int s = 0; s < 2; ++s) {
        int ga = s * 4 + lp;
        bf16x8 a = *(const bf16x8*)(tile + rowb * OTSTR + ((ga ^ (rowb & 7)) << 3));
        bf16x8 bw = ofp[((kk * 2 + s) * 2 + og) * 64 + lane];
        aco = __builtin_amdgcn_mfma_f32_16x16x32_bf16(a, bw, aco, 0, 0, 0);
      }
    }
    if (oc < 18) {
#pragma unroll
      for (int j = 0; j < 4; ++j) offT[oc * 64 + pt * 16 + lp * 4 + j] = aco[j];
    }
  }
  __syncthreads();

#pragma unroll
  for (int it = 0; it < 5; ++it) {
    int idx = it * 256 + t;
    if (idx < 1152) {
      int oc2 = idx >> 6, px = idx & 63;
      off[(size_t)(b * 18 + oc2) * HW_ + y * W_ + x0 + px] = offT[idx];
    }
  }
}

// ---------------- deform (R16 structure, granule-level sampling) ------------
__global__ __launch_bounds__(256, 4) void deform_kernel(
    const unsigned short* __restrict__ pbf, const float* __restrict__ off,
    const unsigned short* __restrict__ wf2, const unsigned short* __restrict__ w1p,
    const unsigned short* __restrict__ w2p, const float* __restrict__ db,
    const float* __restrict__ b1f, const float* __restrict__ b2,
    const float* __restrict__ xin, float* __restrict__ out) {
  __shared__ __align__(16) unsigned short tileTb[100 * TSTR];  // 12800 B
  __shared__ __align__(16) unsigned short sAb[16 * ROWS];      // 19712 B
  __shared__ __align__(16) unsigned short rTb[16 * 72];        // 2304 B
  __shared__ __align__(16) unsigned short hTb[16 * 72];        // 2304 B
  __shared__ uint2 cwb[144];                                   // 1152 B
  __shared__ uchar4 rel4[144];                                 // 576 B
  __shared__ int wOK[4];
  int t = threadIdx.x;
  int lane = t & 63, wv = t >> 6;
  int l15 = lane & 15, lp = lane >> 4;
  int pix0 = blockIdx.x * 16;
  int b = pix0 >> 14;
  int yx0 = pix0 & 16383;
  int y = yx0 >> 7, x0 = yx0 & 127;
  int ty = min(max(y - 2, 0), 123);
  int tx = min(max(x0 - 2, 0), 108);
  const unsigned short* pB = pbf + (size_t)(b * HW_) * 64;

  int o_me = wv * 16 + l15;
  int px0 = lp * 4;
  const float4 xv = *(const float4*)(xin + (size_t)(b * C_ + o_me) * HW_ + yx0 + px0);

  // ---- params: thread t<144 -> job (pixl = t&15, kk = t>>4) ----
  bool ok = true;
  int pixl = t & 15, kk = t >> 4;
  bool active = (t < 144);
  if (active) {
    int xx = x0 + pixl;
    const float* ob = off + (size_t)(b * 18 + kk * 2) * HW_ + y * W_ + xx;
    float offy = ob[0];
    float offx = ob[HW_];
    float sy = (float)(y + (kk / 3) - 1) + offy;
    float sx = (float)(xx + (kk % 3) - 1) + offx;
    float fy = floorf(sy), fx = floorf(sx);
    float wy = sy - fy, wx = sx - fx;
    int iy = (int)fy, ix = (int)fx;
    float w[4];
    int rc[4];
#pragma unroll
    for (int j = 0; j < 4; ++j) {
      int dy = j >> 1, dx = j & 1;
      int yc = iy + dy, xc = ix + dx;
      bool v = ((unsigned)yc < 128u) && ((unsigned)xc < 128u);
      int ycc = min(max(yc, 0), 127), xcc = min(max(xc, 0), 127);
      float wgt = (dy ? wy : 1.f - wy) * (dx ? wx : 1.f - wx);
      w[j] = v ? wgt : 0.f;
      bool in_tile = (ycc >= ty) && (ycc <= ty + 4) && (xcc >= tx) && (xcc <= tx + 19);
      ok = ok && ((w[j] == 0.f) || in_tile);
      int ry = min(max(ycc - ty, 0), 4);
      int rx = min(max(xcc - tx, 0), 19);
      rc[j] = ry * 20 + rx;
    }
    cwb[t] = make_uint2(pack2(w[0], w[1]), pack2(w[2], w[3]));
    rel4[t] = make_uchar4((unsigned char)rc[0], (unsigned char)rc[1],
                          (unsigned char)rc[2], (unsigned char)rc[3]);
    // zero own k-pad strip in sAb (c = 64..67)
    *(uint2*)(sAb + pixl * ROWS + kk * 68 + 64) = make_uint2(0u, 0u);
  }
  {
    unsigned long long m = __ballot(ok);
    if (lane == 0) wOK[wv] = (m == ~0ull) ? 1 : 0;
  }

  // ---- stage tile: 100 rows x 8 granules = 800 chunks of 16B (NHWC copy) ----
#pragma unroll
  for (int it = 0; it < 3; ++it) {
    int ch = it * 256 + t;  // 0..767
    int rc = ch >> 3, g = ch & 7;
    int r = rc / 20, cx = rc - r * 20;
    uint4 v = *(const uint4*)(pB + ((size_t)((ty + r) * W_ + tx + cx)) * 64 + g * 8);
    *(uint4*)(tileTb + rc * TSTR + ((g ^ (rc & 7)) << 3)) = v;
  }
  if (t < 32) {
    int ch = 768 + t;
    int rc = ch >> 3, g = ch & 7;
    int r = rc / 20, cx = rc - r * 20;
    uint4 v = *(const uint4*)(pB + ((size_t)((ty + r) * W_ + tx + cx)) * 64 + g * 8);
    *(uint4*)(tileTb + rc * TSTR + ((g ^ (rc & 7)) << 3)) = v;
  }
  __syncthreads();

  bool fast = wOK[0] && wOK[1] && wOK[2] && wOK[3];

  // ---- sampling: 1152 granule-tasks, 4 dense passes + 1 half pass ----
  if (fast) {
    auto do_gran = [&](int n) {
      int job = n >> 3, g = n & 7;
      int jp = job & 15, jk = job >> 4;
      uint2 wp = cwb[job];
      uchar4 rl = rel4[job];
      float w0 = bfl((unsigned short)(wp.x & 0xffffu));
      float w1_ = bfl((unsigned short)(wp.x >> 16));
      float w2_ = bfl((unsigned short)(wp.y & 0xffffu));
      float w3_ = bfl((unsigned short)(wp.y >> 16));
      bf16x8 v0 = *(const bf16x8*)(tileTb + (int)rl.x * TSTR + ((g ^ (rl.x & 7)) << 3));
      bf16x8 v1 = *(const bf16x8*)(tileTb + (int)rl.y * TSTR + ((g ^ (rl.y & 7)) << 3));
      bf16x8 v2 = *(const bf16x8*)(tileTb + (int)rl.z * TSTR + ((g ^ (rl.z & 7)) << 3));
      bf16x8 v3 = *(const bf16x8*)(tileTb + (int)rl.w * TSTR + ((g ^ (rl.w & 7)) << 3));
      const unsigned* u0 = (const unsigned*)&v0;
      const unsigned* u1 = (const unsigned*)&v1;
      const unsigned* u2 = (const unsigned*)&v2;
      const unsigned* u3 = (const unsigned*)&v3;
      unsigned dws[4];
#pragma unroll
      for (int d = 0; d < 4; ++d) {
        f32x2 c0 = {__uint_as_float(u0[d] << 16), __uint_as_float(u0[d] & 0xffff0000u)};
        f32x2 c1 = {__uint_as_float(u1[d] << 16), __uint_as_float(u1[d] & 0xffff0000u)};
        f32x2 c2 = {__uint_as_float(u2[d] << 16), __uint_as_float(u2[d] & 0xffff0000u)};
        f32x2 c3 = {__uint_as_float(u3[d] << 16), __uint_as_float(u3[d] & 0xffff0000u)};
        f32x2 s = w0 * c0 + w1_ * c1 + w2_ * c2 + w3_ * c3;
        dws[d] = pack2(s[0], s[1]);
      }
      unsigned short* wr = sAb + jp * ROWS + jk * 68 + g * 8;
      *(uint2*)(wr) = make_uint2(dws[0], dws[1]);
      *(uint2*)(wr + 4) = make_uint2(dws[2], dws[3]);
    };
    do_gran(t);
    do_gran(t + 256);
    do_gran(t + 512);
    do_gran(t + 768);
    if (t < 128) do_gran(t + 1024);
  } else {
    if (active) {
      // slow path: recompute corners, sample NHWC bf16 p globally
      int xx = x0 + pixl;
      const float* ob = off + (size_t)(b * 18 + kk * 2) * HW_ + y * W_ + xx;
      float offy = ob[0];
      float offx = ob[HW_];
      float sy = (float)(y + (kk / 3) - 1) + offy;
      float sx = (float)(xx + (kk % 3) - 1) + offx;
      float fy = floorf(sy), fx = floorf(sx);
      float wy = sy - fy, wx = sx - fx;
      int iy = (int)fy, ix = (int)fx;
      float wj[4];
      const unsigned short* pc[4];
#pragma unroll
      for (int j = 0; j < 4; ++j) {
        int dy = j >> 1, dx = j & 1;
        int yc = iy + dy, xc = ix + dx;
        bool v = ((unsigned)yc < 128u) && ((unsigned)xc < 128u);
        int ycc = min(max(yc, 0), 127), xcc = min(max(xc, 0), 127);
        wj[j] = v ? (dy ? wy : 1.f - wy) * (dx ? wx : 1.f - wx) : 0.f;
        pc[j] = pB + ((size_t)(ycc * W_ + xcc)) * 64;
      }
      unsigned short* wr = sAb + pixl * ROWS + kk * 68;
#pragma unroll 4
      for (int c = 0; c < 64; ++c) {
        float v = wj[0] * bfl(pc[0][c]) + wj[1] * bfl(pc[1][c]) +
                  wj[2] * bfl(pc[2][c]) + wj[3] * bfl(pc[3][c]);
        wr[c] = f2bf(v);
      }
    }
  }
  __syncthreads();

  // ---- deform GEMM: 19 slots (proven A/B pairing + D layout) ----
  f32x4 acc;
  {
    float d = db[o_me];
    acc = (f32x4){d, d, d, d};
  }
  const unsigned short* arow = sAb + l15 * ROWS + (lp << 3);
  const bf16x8* wfp = (const bf16x8*)wf2;
#pragma unroll
  for (int s = 0; s < KSLOTS; ++s) {
    bf16x8 a = *(const bf16x8*)(arow + s * 32);
    bf16x8 bw = wfp[(s * 4 + wv) * 64 + lane];
    acc = __builtin_amdgcn_mfma_f32_16x16x32_bf16(a, bw, acc, 0, 0, 0);
  }

#pragma unroll
  for (int j = 0; j < 4; ++j) {
    rTb[(px0 + j) * 72 + o_me] = f2bf(acc[j]);
  }
  __syncthreads();

  // ---- conv1 + BN + ReLU + residual ----
  f32x4 acc1;
  {
    float bb = b1f[o_me];
    acc1 = (f32x4){bb, bb, bb, bb};
  }
  const unsigned short* arow1 = rTb + l15 * 72 + (lp << 3);
  const bf16x8* w1f8 = (const bf16x8*)w1p;
#pragma unroll
  for (int s = 0; s < 2; ++s) {
    bf16x8 a = *(const bf16x8*)(arow1 + s * 32);
    bf16x8 bw = w1f8[(s * 4 + wv) * 64 + lane];
    acc1 = __builtin_amdgcn_mfma_f32_16x16x32_bf16(a, bw, acc1, 0, 0, 0);
  }
  float h0 = fmaxf(acc1[0], 0.f) + xv.x;
  float h1 = fmaxf(acc1[1], 0.f) + xv.y;
  float h2 = fmaxf(acc1[2], 0.f) + xv.z;
  float h3 = fmaxf(acc1[3], 0.f) + xv.w;
  hTb[(px0 + 0) * 72 + o_me] = f2bf(h0);
  hTb[(px0 + 1) * 72 + o_me] = f2bf(h1);
  hTb[(px0 + 2) * 72 + o_me] = f2bf(h2);
  hTb[(px0 + 3) * 72 + o_me] = f2bf(h3);
  __syncthreads();

  // ---- conv2 ----
  f32x4 acc2;
  {
    float bo = b2[o_me];
    acc2 = (f32x4){bo, bo, bo, bo};
  }
  const unsigned short* arow2 = hTb + l15 * 72 + (lp << 3);
  const bf16x8* w2f8 = (const bf16x8*)w2p;
#pragma unroll
  for (int s = 0; s < 2; ++s) {
    bf16x8 a = *(const bf16x8*)(arow2 + s * 32);
    bf16x8 bw = w2f8[(s * 4 + wv) * 64 + lane];
    acc2 = __builtin_amdgcn_mfma_f32_16x16x32_bf16(a, bw, acc2, 0, 0, 0);
  }
  *(float4*)(out + (size_t)(b * C_ + o_me) * HW_ + yx0 + px0) =
      make_float4(acc2[0], acc2[1], acc2[2], acc2[3]);
}

extern "C" void kernel_launch(void* const* d_in, const int* in_sizes, int n_in,
                              void* d_out, int out_size, void* d_ws, size_t ws_size,
                              hipStream_t stream) {
  const float* x = (const float*)d_in[0];
  const float* offw = (const float*)d_in[1];
  const float* offb = (const float*)d_in[2];
  const float* dw = (const float*)d_in[3];
  const float* db = (const float*)d_in[4];
  const float* w1 = (const float*)d_in[5];
  const float* b1 = (const float*)d_in[6];
  const float* gamma = (const float*)d_in[7];
  const float* beta = (const float*)d_in[8];
  const float* rmean = (const float*)d_in[9];
  const float* rvar = (const float*)d_in[10];
  const float* w2 = (const float*)d_in[11];
  const float* b2 = (const float*)d_in[12];
  float* out = (float*)d_out;

  unsigned short* pbf = (unsigned short*)d_ws;      // 8388608 bf16 (NHWC)
  float* off = (float*)(pbf + 8388608);             // 2359296 f
  unsigned short* wf2 = (unsigned short*)(off + 2359296);  // 38912 bf16
  unsigned short* offwp = wf2 + 38912;              // 18432 bf16
  unsigned short* w1p = offwp + 18432;              // 4096 bf16
  unsigned short* w2p = w1p + 4096;                 // 4096 bf16
  float* b1f = (float*)(w2p + 4096);                // 64 f

  prep_kernel<<<257, 256, 0, stream>>>(dw, offw, w1, b1, gamma, beta, rmean,
                                       rvar, w2, wf2, offwp, w1p, w2p, b1f);
  avgpool_kernel<<<2048, 256, 0, stream>>>(x, pbf);
  offconv_kernel<<<2048, 256, 0, stream>>>(pbf, offwp, offb, off);
  deform_kernel<<<8192, 256, 0, stream>>>(pbf, off, wf2, w1p, w2p, db, b1f, b2,
                                          x, out);
}

// Round 18
// 102.841 us; speedup vs baseline: 1.2028x; 1.0617x over previous
//
#include <hip/hip_runtime.h>
#include <hip/hip_bf16.h>
#include <cstddef>

#define H_ 128
#define W_ 128
#define HW_ 16384
#define C_ 64
#define B_ 8
#define EPS_ 1e-5f

#define KSLOTS 18   // deform GEMM k-slots, k = kk*64 + c (exact, no pad)
#define ROWS 584    // sAb row stride (shorts) = 73 x 16B slots (73 odd -> swizzle-clean)
#define TSTR 64     // tile row stride (shorts) = 32 dwords
#define OTSTR 64    // offconv tile row stride (shorts)

typedef __attribute__((ext_vector_type(8))) short bf16x8;
typedef __attribute__((ext_vector_type(4))) float f32x4;
typedef __attribute__((ext_vector_type(2))) float f32x2;

__device__ __forceinline__ unsigned short f2bf(float f) {
  __hip_bfloat16 h = __float2bfloat16(f);
  unsigned short u;
  __builtin_memcpy(&u, &h, 2);
  return u;
}
__device__ __forceinline__ unsigned pack2(float lo, float hi) {
  return (unsigned)f2bf(lo) | ((unsigned)f2bf(hi) << 16);
}
__device__ __forceinline__ float bfl(unsigned short v) {
  return __uint_as_float(((unsigned)v) << 16);
}

// ------- avgpool (blocks 0..2047) + weight prep (blocks 2048..2304) ---------
__global__ __launch_bounds__(256) void pool_prep_kernel(
    const float* __restrict__ xin, unsigned short* __restrict__ pbf,
    const float* __restrict__ dw, const float* __restrict__ offw,
    const float* __restrict__ w1, const float* __restrict__ b1,
    const float* __restrict__ gamma, const float* __restrict__ beta,
    const float* __restrict__ rmean, const float* __restrict__ rvar,
    const float* __restrict__ w2,
    unsigned short* __restrict__ wf2, unsigned short* __restrict__ offwp,
    unsigned short* __restrict__ w1p, unsigned short* __restrict__ w2p,
    float* __restrict__ b1f) {
  int t = threadIdx.x;
  int blk = blockIdx.x;
  if (blk >= 2048) {
    // ---- prep body ----
    int i = (blk - 2048) * 256 + t;
    if (i < 36864) {  // deform: 18 sg * 4 og * 64 l * 8 j, k = kk*64 + c
      int j = i & 7, l = (i >> 3) & 63, og = (i >> 9) & 3, sg = i >> 11;
      int o = og * 16 + (l & 15);
      int k = sg * 32 + ((l >> 4) << 3) + j;  // 0..575
      int kk = k >> 6, c = k & 63;
      wf2[i] = f2bf(dw[o * 576 + c * 9 + kk]);
    } else if (i < 36864 + 18432) {  // offconv: 18 slot * 2 og * 64 l * 8 j
      int j2 = i - 36864;
      int j = j2 & 7, l = (j2 >> 3) & 63, og = (j2 >> 9) & 1, slot = j2 >> 10;
      int kk = slot >> 1, s = slot & 1;
      int oc = og * 16 + (l & 15);
      int c = s * 32 + ((l >> 4) << 3) + j;
      float v = (oc < 18) ? offw[oc * 576 + c * 9 + kk] : 0.f;
      offwp[j2] = f2bf(v);
    } else if (i < 36864 + 18432 + 4096) {
      int j2 = i - 36864 - 18432;
      int j = j2 & 7, l = (j2 >> 3) & 63, og = (j2 >> 9) & 3, sg = j2 >> 11;
      int o = og * 16 + (l & 15);
      int c = sg * 32 + ((l >> 4) << 3) + j;
      float inv = gamma[o] * rsqrtf(rvar[o] + EPS_);
      w1p[j2] = f2bf(w1[o * 64 + c] * inv);
    } else if (i < 36864 + 18432 + 8192) {
      int j2 = i - 36864 - 18432 - 4096;
      int j = j2 & 7, l = (j2 >> 3) & 63, og = (j2 >> 9) & 3, sg = j2 >> 11;
      int o = og * 16 + (l & 15);
      int c = sg * 32 + ((l >> 4) << 3) + j;
      w2p[j2] = f2bf(w2[o * 64 + c]);
    } else if (i < 36864 + 18432 + 8192 + 64) {
      int o = i - 36864 - 18432 - 8192;
      float inv = gamma[o] * rsqrtf(rvar[o] + EPS_);
      b1f[o] = b1[o] * inv + beta[o] - rmean[o] * inv;
    }
    return;
  }
  // ---- avgpool body (R14-proven) ----
  __shared__ __align__(16) unsigned short pool[64 * 72];
  int c = t & 63, wvp = t >> 6;
  int half = blk & 1;
  int row = blk >> 1;
  int b = row >> 7, y = row & 127;
  int xb = half * 64 + wvp * 16;
  const float* q = xin + (size_t)(b * C_ + c) * HW_;

  float ver[16];
#pragma unroll
  for (int i = 0; i < 16; ++i) ver[i] = 0.f;
#pragma unroll
  for (int dy = -1; dy <= 1; ++dy) {
    int yy = y + dy;
    if ((unsigned)yy < 128u) {
      const float* r = q + yy * W_;
      float m[18];
      m[0] = (xb > 0) ? r[xb - 1] : 0.f;
      float4 v0 = *(const float4*)(r + xb);
      float4 v1 = *(const float4*)(r + xb + 4);
      float4 v2 = *(const float4*)(r + xb + 8);
      float4 v3 = *(const float4*)(r + xb + 12);
      m[1] = v0.x; m[2] = v0.y; m[3] = v0.z; m[4] = v0.w;
      m[5] = v1.x; m[6] = v1.y; m[7] = v1.z; m[8] = v1.w;
      m[9] = v2.x; m[10] = v2.y; m[11] = v2.z; m[12] = v2.w;
      m[13] = v3.x; m[14] = v3.y; m[15] = v3.z; m[16] = v3.w;
      m[17] = (xb < 112) ? r[xb + 16] : 0.f;
#pragma unroll
      for (int i = 0; i < 16; ++i) ver[i] += m[i] + m[i + 1] + m[i + 2];
    }
  }
  int pxb = wvp * 16;
#pragma unroll
  for (int i = 0; i < 16; ++i) {
    int px = pxb + i;
    int cg = c >> 3;
    pool[px * 72 + ((cg ^ (px & 7)) << 3) + (c & 7)] = f2bf(ver[i] * (1.f / 9.f));
  }
  __syncthreads();

  size_t base = ((size_t)(b * HW_) + y * W_ + half * 64) * 64;
#pragma unroll
  for (int k = 0; k < 2; ++k) {
    int ch = k * 256 + t;
    int px = ch >> 3, g = ch & 7;
    uint2 v = *(const uint2*)(pool + px * 72 + ((g ^ (px & 7)) << 3));
    uint2 v2 = *(const uint2*)(pool + px * 72 + ((g ^ (px & 7)) << 3) + 4);
    *(uint4*)(pbf + base + px * 64 + g * 8) = make_uint4(v.x, v.y, v2.x, v2.y);
  }
}

// ---------------- offset conv via MFMA (R16-proven) ----------------
__global__ __launch_bounds__(256, 4) void offconv_kernel(
    const unsigned short* __restrict__ pbf, const unsigned short* __restrict__ offwp,
    const float* __restrict__ offb, float* __restrict__ off) {
  __shared__ __align__(16) unsigned short tile[198 * OTSTR];  // 25344 B
  __shared__ float offT[18 * 64];                             // 4608 B
  int t = threadIdx.x;
  int lane = t & 63, wv = t >> 6;
  int l15 = lane & 15, lp = lane >> 4;
  int blk = blockIdx.x;
  int half = blk & 1;
  int row = blk >> 1;
  int b = row >> 7, y = row & 127;
  int x0 = half * 64;

#pragma unroll
  for (int it = 0; it < 7; ++it) {
    int ch = it * 256 + t;
    if (ch < 1584) {
      int rc = ch >> 3, g = ch & 7;
      int r = rc / 66, cx = rc - r * 66;
      int iy = y - 1 + r, ix = x0 - 1 + cx;
      uint4 v = make_uint4(0u, 0u, 0u, 0u);
      if (((unsigned)iy < 128u) && ((unsigned)ix < 128u)) {
        v = *(const uint4*)(pbf + ((size_t)(b * HW_) + iy * W_ + ix) * 64 + g * 8);
      }
      *(uint4*)(tile + rc * OTSTR + ((g ^ (rc & 7)) << 3)) = v;
    }
  }
  __syncthreads();

  int og = wv & 1;
  int oc = og * 16 + l15;
  float bo = offb[min(oc, 17)];
  const bf16x8* ofp = (const bf16x8*)offwp;
#pragma unroll
  for (int pti = 0; pti < 2; ++pti) {
    int pt = (wv >> 1) + pti * 2;
    f32x4 aco = (f32x4){bo, bo, bo, bo};
#pragma unroll
    for (int kk = 0; kk < 9; ++kk) {
      int rowb = (kk / 3) * 66 + (kk % 3) + pt * 16 + l15;
#pragma unroll
      for (int s = 0; s < 2; ++s) {
        int ga = s * 4 + lp;
        bf16x8 a = *(const bf16x8*)(tile + rowb * OTSTR + ((ga ^ (rowb & 7)) << 3));
        bf16x8 bw = ofp[((kk * 2 + s) * 2 + og) * 64 + lane];
        aco = __builtin_amdgcn_mfma_f32_16x16x32_bf16(a, bw, aco, 0, 0, 0);
      }
    }
    if (oc < 18) {
#pragma unroll
      for (int j = 0; j < 4; ++j) offT[oc * 64 + pt * 16 + lp * 4 + j] = aco[j];
    }
  }
  __syncthreads();

#pragma unroll
  for (int it = 0; it < 5; ++it) {
    int idx = it * 256 + t;
    if (idx < 1152) {
      int oc2 = idx >> 6, px = idx & 63;
      off[(size_t)(b * 18 + oc2) * HW_ + y * W_ + x0 + px] = offT[idx];
    }
  }
}

// ---------------- deform (R17 structure, 18-slot exact k-map) ---------------
__global__ __launch_bounds__(256, 4) void deform_kernel(
    const unsigned short* __restrict__ pbf, const float* __restrict__ off,
    const unsigned short* __restrict__ wf2, const unsigned short* __restrict__ w1p,
    const unsigned short* __restrict__ w2p, const float* __restrict__ db,
    const float* __restrict__ b1f, const float* __restrict__ b2,
    const float* __restrict__ xin, float* __restrict__ out) {
  __shared__ __align__(16) unsigned short tileTb[100 * TSTR];  // 12800 B
  __shared__ __align__(16) unsigned short sAb[16 * ROWS];      // 18688 B
  __shared__ __align__(16) unsigned short rTb[16 * 72];        // 2304 B
  __shared__ __align__(16) unsigned short hTb[16 * 72];        // 2304 B
  __shared__ uint2 cwb[144];                                   // 1152 B
  __shared__ uchar4 rel4[144];                                 // 576 B
  __shared__ int wOK[4];
  int t = threadIdx.x;
  int lane = t & 63, wv = t >> 6;
  int l15 = lane & 15, lp = lane >> 4;
  int pix0 = blockIdx.x * 16;
  int b = pix0 >> 14;
  int yx0 = pix0 & 16383;
  int y = yx0 >> 7, x0 = yx0 & 127;
  int ty = min(max(y - 2, 0), 123);
  int tx = min(max(x0 - 2, 0), 108);
  const unsigned short* pB = pbf + (size_t)(b * HW_) * 64;

  int o_me = wv * 16 + l15;
  int px0 = lp * 4;
  const float4 xv = *(const float4*)(xin + (size_t)(b * C_ + o_me) * HW_ + yx0 + px0);

  // ---- params: thread t<144 -> job (pixl = t&15, kk = t>>4) ----
  bool ok = true;
  int pixl = t & 15, kk = t >> 4;
  bool active = (t < 144);
  if (active) {
    int xx = x0 + pixl;
    const float* ob = off + (size_t)(b * 18 + kk * 2) * HW_ + y * W_ + xx;
    float offy = ob[0];
    float offx = ob[HW_];
    float sy = (float)(y + (kk / 3) - 1) + offy;
    float sx = (float)(xx + (kk % 3) - 1) + offx;
    float fy = floorf(sy), fx = floorf(sx);
    float wy = sy - fy, wx = sx - fx;
    int iy = (int)fy, ix = (int)fx;
    float w[4];
    int rc[4];
#pragma unroll
    for (int j = 0; j < 4; ++j) {
      int dy = j >> 1, dx = j & 1;
      int yc = iy + dy, xc = ix + dx;
      bool v = ((unsigned)yc < 128u) && ((unsigned)xc < 128u);
      int ycc = min(max(yc, 0), 127), xcc = min(max(xc, 0), 127);
      float wgt = (dy ? wy : 1.f - wy) * (dx ? wx : 1.f - wx);
      w[j] = v ? wgt : 0.f;
      bool in_tile = (ycc >= ty) && (ycc <= ty + 4) && (xcc >= tx) && (xcc <= tx + 19);
      ok = ok && ((w[j] == 0.f) || in_tile);
      int ry = min(max(ycc - ty, 0), 4);
      int rx = min(max(xcc - tx, 0), 19);
      rc[j] = ry * 20 + rx;
    }
    cwb[t] = make_uint2(pack2(w[0], w[1]), pack2(w[2], w[3]));
    rel4[t] = make_uchar4((unsigned char)rc[0], (unsigned char)rc[1],
                          (unsigned char)rc[2], (unsigned char)rc[3]);
  }
  {
    unsigned long long m = __ballot(ok);
    if (lane == 0) wOK[wv] = (m == ~0ull) ? 1 : 0;
  }

  // ---- stage tile: 100 rows x 8 granules = 800 chunks of 16B (NHWC copy) ----
#pragma unroll
  for (int it = 0; it < 3; ++it) {
    int ch = it * 256 + t;  // 0..767
    int rc = ch >> 3, g = ch & 7;
    int r = rc / 20, cx = rc - r * 20;
    uint4 v = *(const uint4*)(pB + ((size_t)((ty + r) * W_ + tx + cx)) * 64 + g * 8);
    *(uint4*)(tileTb + rc * TSTR + ((g ^ (rc & 7)) << 3)) = v;
  }
  if (t < 32) {
    int ch = 768 + t;
    int rc = ch >> 3, g = ch & 7;
    int r = rc / 20, cx = rc - r * 20;
    uint4 v = *(const uint4*)(pB + ((size_t)((ty + r) * W_ + tx + cx)) * 64 + g * 8);
    *(uint4*)(tileTb + rc * TSTR + ((g ^ (rc & 7)) << 3)) = v;
  }
  __syncthreads();

  bool fast = wOK[0] && wOK[1] && wOK[2] && wOK[3];

  // ---- sampling: 1152 granule-tasks, 4 dense passes + 1 half pass ----
  if (fast) {
    auto do_gran = [&](int n) {
      int job = n >> 3, g = n & 7;
      int jp = job & 15, jk = job >> 4;
      uint2 wp = cwb[job];
      uchar4 rl = rel4[job];
      float w0 = bfl((unsigned short)(wp.x & 0xffffu));
      float w1_ = bfl((unsigned short)(wp.x >> 16));
      float w2_ = bfl((unsigned short)(wp.y & 0xffffu));
      float w3_ = bfl((unsigned short)(wp.y >> 16));
      bf16x8 v0 = *(const bf16x8*)(tileTb + (int)rl.x * TSTR + ((g ^ (rl.x & 7)) << 3));
      bf16x8 v1 = *(const bf16x8*)(tileTb + (int)rl.y * TSTR + ((g ^ (rl.y & 7)) << 3));
      bf16x8 v2 = *(const bf16x8*)(tileTb + (int)rl.z * TSTR + ((g ^ (rl.z & 7)) << 3));
      bf16x8 v3 = *(const bf16x8*)(tileTb + (int)rl.w * TSTR + ((g ^ (rl.w & 7)) << 3));
      const unsigned* u0 = (const unsigned*)&v0;
      const unsigned* u1 = (const unsigned*)&v1;
      const unsigned* u2 = (const unsigned*)&v2;
      const unsigned* u3 = (const unsigned*)&v3;
      unsigned dws[4];
#pragma unroll
      for (int d = 0; d < 4; ++d) {
        f32x2 c0 = {__uint_as_float(u0[d] << 16), __uint_as_float(u0[d] & 0xffff0000u)};
        f32x2 c1 = {__uint_as_float(u1[d] << 16), __uint_as_float(u1[d] & 0xffff0000u)};
        f32x2 c2 = {__uint_as_float(u2[d] << 16), __uint_as_float(u2[d] & 0xffff0000u)};
        f32x2 c3 = {__uint_as_float(u3[d] << 16), __uint_as_float(u3[d] & 0xffff0000u)};
        f32x2 s = w0 * c0 + w1_ * c1 + w2_ * c2 + w3_ * c3;
        dws[d] = pack2(s[0], s[1]);
      }
      // single 16B-aligned write: jp*584 (73x16B) + jk*64 (8x16B... 128B) + g*8 (16B)
      *(uint4*)(sAb + jp * ROWS + jk * 64 + g * 8) =
          make_uint4(dws[0], dws[1], dws[2], dws[3]);
    };
    do_gran(t);
    do_gran(t + 256);
    do_gran(t + 512);
    do_gran(t + 768);
    if (t < 128) do_gran(t + 1024);
  } else {
    if (active) {
      // slow path: recompute corners, sample NHWC bf16 p globally
      int xx = x0 + pixl;
      const float* ob = off + (size_t)(b * 18 + kk * 2) * HW_ + y * W_ + xx;
      float offy = ob[0];
      float offx = ob[HW_];
      float sy = (float)(y + (kk / 3) - 1) + offy;
      float sx = (float)(xx + (kk % 3) - 1) + offx;
      float fy = floorf(sy), fx = floorf(sx);
      float wy = sy - fy, wx = sx - fx;
      int iy = (int)fy, ix = (int)fx;
      float wj[4];
      const unsigned short* pc[4];
#pragma unroll
      for (int j = 0; j < 4; ++j) {
        int dy = j >> 1, dx = j & 1;
        int yc = iy + dy, xc = ix + dx;
        bool v = ((unsigned)yc < 128u) && ((unsigned)xc < 128u);
        int ycc = min(max(yc, 0), 127), xcc = min(max(xc, 0), 127);
        wj[j] = v ? (dy ? wy : 1.f - wy) * (dx ? wx : 1.f - wx) : 0.f;
        pc[j] = pB + ((size_t)(ycc * W_ + xcc)) * 64;
      }
      unsigned short* wr = sAb + pixl * ROWS + kk * 64;
#pragma unroll 4
      for (int c = 0; c < 64; ++c) {
        float v = wj[0] * bfl(pc[0][c]) + wj[1] * bfl(pc[1][c]) +
                  wj[2] * bfl(pc[2][c]) + wj[3] * bfl(pc[3][c]);
        wr[c] = f2bf(v);
      }
    }
  }
  __syncthreads();

  // ---- deform GEMM: 18 slots (proven A/B pairing + D layout) ----
  f32x4 acc;
  {
    float d = db[o_me];
    acc = (f32x4){d, d, d, d};
  }
  const unsigned short* arow = sAb + l15 * ROWS + (lp << 3);
  const bf16x8* wfp = (const bf16x8*)wf2;
#pragma unroll
  for (int s = 0; s < KSLOTS; ++s) {
    bf16x8 a = *(const bf16x8*)(arow + s * 32);
    bf16x8 bw = wfp[(s * 4 + wv) * 64 + lane];
    acc = __builtin_amdgcn_mfma_f32_16x16x32_bf16(a, bw, acc, 0, 0, 0);
  }

#pragma unroll
  for (int j = 0; j < 4; ++j) {
    rTb[(px0 + j) * 72 + o_me] = f2bf(acc[j]);
  }
  __syncthreads();

  // ---- conv1 + BN + ReLU + residual ----
  f32x4 acc1;
  {
    float bb = b1f[o_me];
    acc1 = (f32x4){bb, bb, bb, bb};
  }
  const unsigned short* arow1 = rTb + l15 * 72 + (lp << 3);
  const bf16x8* w1f8 = (const bf16x8*)w1p;
#pragma unroll
  for (int s = 0; s < 2; ++s) {
    bf16x8 a = *(const bf16x8*)(arow1 + s * 32);
    bf16x8 bw = w1f8[(s * 4 + wv) * 64 + lane];
    acc1 = __builtin_amdgcn_mfma_f32_16x16x32_bf16(a, bw, acc1, 0, 0, 0);
  }
  float h0 = fmaxf(acc1[0], 0.f) + xv.x;
  float h1 = fmaxf(acc1[1], 0.f) + xv.y;
  float h2 = fmaxf(acc1[2], 0.f) + xv.z;
  float h3 = fmaxf(acc1[3], 0.f) + xv.w;
  hTb[(px0 + 0) * 72 + o_me] = f2bf(h0);
  hTb[(px0 + 1) * 72 + o_me] = f2bf(h1);
  hTb[(px0 + 2) * 72 + o_me] = f2bf(h2);
  hTb[(px0 + 3) * 72 + o_me] = f2bf(h3);
  __syncthreads();

  // ---- conv2 ----
  f32x4 acc2;
  {
    float bo = b2[o_me];
    acc2 = (f32x4){bo, bo, bo, bo};
  }
  const unsigned short* arow2 = hTb + l15 * 72 + (lp << 3);
  const bf16x8* w2f8 = (const bf16x8*)w2p;
#pragma unroll
  for (int s = 0; s < 2; ++s) {
    bf16x8 a = *(const bf16x8*)(arow2 + s * 32);
    bf16x8 bw = w2f8[(s * 4 + wv) * 64 + lane];
    acc2 = __builtin_amdgcn_mfma_f32_16x16x32_bf16(a, bw, acc2, 0, 0, 0);
  }
  *(float4*)(out + (size_t)(b * C_ + o_me) * HW_ + yx0 + px0) =
      make_float4(acc2[0], acc2[1], acc2[2], acc2[3]);
}

extern "C" void kernel_launch(void* const* d_in, const int* in_sizes, int n_in,
                              void* d_out, int out_size, void* d_ws, size_t ws_size,
                              hipStream_t stream) {
  const float* x = (const float*)d_in[0];
  const float* offw = (const float*)d_in[1];
  const float* offb = (const float*)d_in[2];
  const float* dw = (const float*)d_in[3];
  const float* db = (const float*)d_in[4];
  const float* w1 = (const float*)d_in[5];
  const float* b1 = (const float*)d_in[6];
  const float* gamma = (const float*)d_in[7];
  const float* beta = (const float*)d_in[8];
  const float* rmean = (const float*)d_in[9];
  const float* rvar = (const float*)d_in[10];
  const float* w2 = (const float*)d_in[11];
  const float* b2 = (const float*)d_in[12];
  float* out = (float*)d_out;

  unsigned short* pbf = (unsigned short*)d_ws;      // 8388608 bf16 (NHWC)
  float* off = (float*)(pbf + 8388608);             // 2359296 f
  unsigned short* wf2 = (unsigned short*)(off + 2359296);  // 36864 bf16
  unsigned short* offwp = wf2 + 36864;              // 18432 bf16
  unsigned short* w1p = offwp + 18432;              // 4096 bf16
  unsigned short* w2p = w1p + 4096;                 // 4096 bf16
  float* b1f = (float*)(w2p + 4096);                // 64 f

  // blocks 0..2047: avgpool; 2048..2304: weight prep (covers 67648 items)
  pool_prep_kernel<<<2305, 256, 0, stream>>>(x, pbf, dw, offw, w1, b1, gamma,
                                             beta, rmean, rvar, w2, wf2, offwp,
                                             w1p, w2p, b1f);
  offconv_kernel<<<2048, 256, 0, stream>>>(pbf, offwp, offb, off);
  deform_kernel<<<8192, 256, 0, stream>>>(pbf, off, wf2, w1p, w2p, db, b1f, b2,
                                          x, out);
}

// Round 19
// 102.083 us; speedup vs baseline: 1.2118x; 1.0074x over previous
//
#include <hip/hip_runtime.h>
#include <hip/hip_bf16.h>
#include <cstddef>

#define H_ 128
#define W_ 128
#define HW_ 16384
#define C_ 64
#define B_ 8
#define EPS_ 1e-5f

#define KSLOTS 18   // deform GEMM k-slots, k = kk*64 + c (exact, no pad)
#define ROWS 584    // sAb row stride (shorts) = 73 x 16B slots
#define TSTR 64     // tile row stride (shorts)
#define OTSTR 64    // offconv tile row stride (shorts)

typedef __attribute__((ext_vector_type(8))) short bf16x8;
typedef __attribute__((ext_vector_type(4))) float f32x4;
typedef __attribute__((ext_vector_type(2))) float f32x2;

__device__ __forceinline__ unsigned short f2bf(float f) {
  __hip_bfloat16 h = __float2bfloat16(f);
  unsigned short u;
  __builtin_memcpy(&u, &h, 2);
  return u;
}
__device__ __forceinline__ unsigned pack2(float lo, float hi) {
  return (unsigned)f2bf(lo) | ((unsigned)f2bf(hi) << 16);
}
__device__ __forceinline__ float bfl(unsigned short v) {
  return __uint_as_float(((unsigned)v) << 16);
}

// ------- avgpool (blocks 0..2047) + weight prep (blocks 2048..2304) ---------
__global__ __launch_bounds__(256) void pool_prep_kernel(
    const float* __restrict__ xin, unsigned short* __restrict__ pbf,
    const float* __restrict__ dw, const float* __restrict__ offw,
    const float* __restrict__ w1, const float* __restrict__ b1,
    const float* __restrict__ gamma, const float* __restrict__ beta,
    const float* __restrict__ rmean, const float* __restrict__ rvar,
    const float* __restrict__ w2,
    unsigned short* __restrict__ wf2, unsigned short* __restrict__ offwp,
    unsigned short* __restrict__ w1p, unsigned short* __restrict__ w2p,
    float* __restrict__ b1f) {
  int t = threadIdx.x;
  int blk = blockIdx.x;
  if (blk >= 2048) {
    int i = (blk - 2048) * 256 + t;
    if (i < 36864) {  // deform: 18 sg * 4 og * 64 l * 8 j, k = kk*64 + c
      int j = i & 7, l = (i >> 3) & 63, og = (i >> 9) & 3, sg = i >> 11;
      int o = og * 16 + (l & 15);
      int k = sg * 32 + ((l >> 4) << 3) + j;
      int kk = k >> 6, c = k & 63;
      wf2[i] = f2bf(dw[o * 576 + c * 9 + kk]);
    } else if (i < 36864 + 18432) {
      int j2 = i - 36864;
      int j = j2 & 7, l = (j2 >> 3) & 63, og = (j2 >> 9) & 1, slot = j2 >> 10;
      int kk = slot >> 1, s = slot & 1;
      int oc = og * 16 + (l & 15);
      int c = s * 32 + ((l >> 4) << 3) + j;
      float v = (oc < 18) ? offw[oc * 576 + c * 9 + kk] : 0.f;
      offwp[j2] = f2bf(v);
    } else if (i < 36864 + 18432 + 4096) {
      int j2 = i - 36864 - 18432;
      int j = j2 & 7, l = (j2 >> 3) & 63, og = (j2 >> 9) & 3, sg = j2 >> 11;
      int o = og * 16 + (l & 15);
      int c = sg * 32 + ((l >> 4) << 3) + j;
      float inv = gamma[o] * rsqrtf(rvar[o] + EPS_);
      w1p[j2] = f2bf(w1[o * 64 + c] * inv);
    } else if (i < 36864 + 18432 + 8192) {
      int j2 = i - 36864 - 18432 - 4096;
      int j = j2 & 7, l = (j2 >> 3) & 63, og = (j2 >> 9) & 3, sg = j2 >> 11;
      int o = og * 16 + (l & 15);
      int c = sg * 32 + ((l >> 4) << 3) + j;
      w2p[j2] = f2bf(w2[o * 64 + c]);
    } else if (i < 36864 + 18432 + 8192 + 64) {
      int o = i - 36864 - 18432 - 8192;
      float inv = gamma[o] * rsqrtf(rvar[o] + EPS_);
      b1f[o] = b1[o] * inv + beta[o] - rmean[o] * inv;
    }
    return;
  }
  __shared__ __align__(16) unsigned short pool[64 * 72];
  int c = t & 63, wvp = t >> 6;
  int half = blk & 1;
  int row = blk >> 1;
  int b = row >> 7, y = row & 127;
  int xb = half * 64 + wvp * 16;
  const float* q = xin + (size_t)(b * C_ + c) * HW_;

  float ver[16];
#pragma unroll
  for (int i = 0; i < 16; ++i) ver[i] = 0.f;
#pragma unroll
  for (int dy = -1; dy <= 1; ++dy) {
    int yy = y + dy;
    if ((unsigned)yy < 128u) {
      const float* r = q + yy * W_;
      float m[18];
      m[0] = (xb > 0) ? r[xb - 1] : 0.f;
      float4 v0 = *(const float4*)(r + xb);
      float4 v1 = *(const float4*)(r + xb + 4);
      float4 v2 = *(const float4*)(r + xb + 8);
      float4 v3 = *(const float4*)(r + xb + 12);
      m[1] = v0.x; m[2] = v0.y; m[3] = v0.z; m[4] = v0.w;
      m[5] = v1.x; m[6] = v1.y; m[7] = v1.z; m[8] = v1.w;
      m[9] = v2.x; m[10] = v2.y; m[11] = v2.z; m[12] = v2.w;
      m[13] = v3.x; m[14] = v3.y; m[15] = v3.z; m[16] = v3.w;
      m[17] = (xb < 112) ? r[xb + 16] : 0.f;
#pragma unroll
      for (int i = 0; i < 16; ++i) ver[i] += m[i] + m[i + 1] + m[i + 2];
    }
  }
  int pxb = wvp * 16;
#pragma unroll
  for (int i = 0; i < 16; ++i) {
    int px = pxb + i;
    int cg = c >> 3;
    pool[px * 72 + ((cg ^ (px & 7)) << 3) + (c & 7)] = f2bf(ver[i] * (1.f / 9.f));
  }
  __syncthreads();

  size_t base = ((size_t)(b * HW_) + y * W_ + half * 64) * 64;
#pragma unroll
  for (int k = 0; k < 2; ++k) {
    int ch = k * 256 + t;
    int px = ch >> 3, g = ch & 7;
    uint2 v = *(const uint2*)(pool + px * 72 + ((g ^ (px & 7)) << 3));
    uint2 v2 = *(const uint2*)(pool + px * 72 + ((g ^ (px & 7)) << 3) + 4);
    *(uint4*)(pbf + base + px * 64 + g * 8) = make_uint4(v.x, v.y, v2.x, v2.y);
  }
}

// ---------------- offset conv via MFMA -> bf16 off ----------------
__global__ __launch_bounds__(256, 4) void offconv_kernel(
    const unsigned short* __restrict__ pbf, const unsigned short* __restrict__ offwp,
    const float* __restrict__ offb, unsigned short* __restrict__ offo) {
  __shared__ __align__(16) unsigned short tile[198 * OTSTR];  // 25344 B
  __shared__ unsigned short offTb[18 * 64];                   // 2304 B
  int t = threadIdx.x;
  int lane = t & 63, wv = t >> 6;
  int l15 = lane & 15, lp = lane >> 4;
  int blk = blockIdx.x;
  int half = blk & 1;
  int row = blk >> 1;
  int b = row >> 7, y = row & 127;
  int x0 = half * 64;

#pragma unroll
  for (int it = 0; it < 7; ++it) {
    int ch = it * 256 + t;
    if (ch < 1584) {
      int rc = ch >> 3, g = ch & 7;
      int r = rc / 66, cx = rc - r * 66;
      int iy = y - 1 + r, ix = x0 - 1 + cx;
      uint4 v = make_uint4(0u, 0u, 0u, 0u);
      if (((unsigned)iy < 128u) && ((unsigned)ix < 128u)) {
        v = *(const uint4*)(pbf + ((size_t)(b * HW_) + iy * W_ + ix) * 64 + g * 8);
      }
      *(uint4*)(tile + rc * OTSTR + ((g ^ (rc & 7)) << 3)) = v;
    }
  }
  __syncthreads();

  int og = wv & 1;
  int oc = og * 16 + l15;
  float bo = offb[min(oc, 17)];
  const bf16x8* ofp = (const bf16x8*)offwp;
#pragma unroll
  for (int pti = 0; pti < 2; ++pti) {
    int pt = (wv >> 1) + pti * 2;
    f32x4 aco = (f32x4){bo, bo, bo, bo};
#pragma unroll
    for (int kk = 0; kk < 9; ++kk) {
      int rowb = (kk / 3) * 66 + (kk % 3) + pt * 16 + l15;
#pragma unroll
      for (int s = 0; s < 2; ++s) {
        int ga = s * 4 + lp;
        bf16x8 a = *(const bf16x8*)(tile + rowb * OTSTR + ((ga ^ (rowb & 7)) << 3));
        bf16x8 bw = ofp[((kk * 2 + s) * 2 + og) * 64 + lane];
        aco = __builtin_amdgcn_mfma_f32_16x16x32_bf16(a, bw, aco, 0, 0, 0);
      }
    }
    if (oc < 18) {
#pragma unroll
      for (int j = 0; j < 4; ++j) offTb[oc * 64 + pt * 16 + lp * 4 + j] = f2bf(aco[j]);
    }
  }
  __syncthreads();

  // paired-dword coalesced store of bf16 offsets
#pragma unroll
  for (int it = 0; it < 3; ++it) {
    int idx = it * 256 + t;
    if (idx < 576) {
      int oc2 = idx >> 5, pxp = (idx & 31) * 2;
      unsigned v = (unsigned)offTb[oc2 * 64 + pxp] |
                   ((unsigned)offTb[oc2 * 64 + pxp + 1] << 16);
      *(unsigned*)(offo + (size_t)(b * 18 + oc2) * HW_ + y * W_ + x0 + pxp) = v;
    }
  }
}

// ---------------- deform (R18 structure + 9-slot B preload, bf16 off) -------
__global__ __launch_bounds__(256, 4) void deform_kernel(
    const unsigned short* __restrict__ pbf, const unsigned short* __restrict__ offo,
    const unsigned short* __restrict__ wf2, const unsigned short* __restrict__ w1p,
    const unsigned short* __restrict__ w2p, const float* __restrict__ db,
    const float* __restrict__ b1f, const float* __restrict__ b2,
    const float* __restrict__ xin, float* __restrict__ out) {
  __shared__ __align__(16) unsigned short tileTb[100 * TSTR];  // 12800 B
  __shared__ __align__(16) unsigned short sAb[16 * ROWS];      // 18688 B
  __shared__ __align__(16) unsigned short rTb[16 * 72];        // 2304 B
  __shared__ __align__(16) unsigned short hTb[16 * 72];        // 2304 B
  __shared__ uint2 cwb[144];                                   // 1152 B
  __shared__ uchar4 rel4[144];                                 // 576 B
  __shared__ int wOK[4];
  int t = threadIdx.x;
  int lane = t & 63, wv = t >> 6;
  int l15 = lane & 15, lp = lane >> 4;
  int pix0 = blockIdx.x * 16;
  int b = pix0 >> 14;
  int yx0 = pix0 & 16383;
  int y = yx0 >> 7, x0 = yx0 & 127;
  int ty = min(max(y - 2, 0), 123);
  int tx = min(max(x0 - 2, 0), 108);
  const unsigned short* pB = pbf + (size_t)(b * HW_) * 64;

  int o_me = wv * 16 + l15;
  int px0 = lp * 4;
  const float4 xv = *(const float4*)(xin + (size_t)(b * C_ + o_me) * HW_ + yx0 + px0);

  // ---- early preload of GEMM B-fragments, slots 0..8 (hides L2 latency) ----
  const bf16x8* wfp = (const bf16x8*)wf2;
  bf16x8 bwr0 = wfp[(0 * 4 + wv) * 64 + lane];
  bf16x8 bwr1 = wfp[(1 * 4 + wv) * 64 + lane];
  bf16x8 bwr2 = wfp[(2 * 4 + wv) * 64 + lane];
  bf16x8 bwr3 = wfp[(3 * 4 + wv) * 64 + lane];
  bf16x8 bwr4 = wfp[(4 * 4 + wv) * 64 + lane];
  bf16x8 bwr5 = wfp[(5 * 4 + wv) * 64 + lane];
  bf16x8 bwr6 = wfp[(6 * 4 + wv) * 64 + lane];
  bf16x8 bwr7 = wfp[(7 * 4 + wv) * 64 + lane];
  bf16x8 bwr8 = wfp[(8 * 4 + wv) * 64 + lane];

  // ---- params: thread t<144 -> job (pixl = t&15, kk = t>>4) ----
  bool ok = true;
  int pixl = t & 15, kk = t >> 4;
  bool active = (t < 144);
  if (active) {
    int xx = x0 + pixl;
    const unsigned short* ob = offo + (size_t)(b * 18 + kk * 2) * HW_ + y * W_ + xx;
    float offy = bfl(ob[0]);
    float offx = bfl(ob[HW_]);
    float sy = (float)(y + (kk / 3) - 1) + offy;
    float sx = (float)(xx + (kk % 3) - 1) + offx;
    float fy = floorf(sy), fx = floorf(sx);
    float wy = sy - fy, wx = sx - fx;
    int iy = (int)fy, ix = (int)fx;
    float w[4];
    int rc[4];
#pragma unroll
    for (int j = 0; j < 4; ++j) {
      int dy = j >> 1, dx = j & 1;
      int yc = iy + dy, xc = ix + dx;
      bool v = ((unsigned)yc < 128u) && ((unsigned)xc < 128u);
      int ycc = min(max(yc, 0), 127), xcc = min(max(xc, 0), 127);
      float wgt = (dy ? wy : 1.f - wy) * (dx ? wx : 1.f - wx);
      w[j] = v ? wgt : 0.f;
      bool in_tile = (ycc >= ty) && (ycc <= ty + 4) && (xcc >= tx) && (xcc <= tx + 19);
      ok = ok && ((w[j] == 0.f) || in_tile);
      int ry = min(max(ycc - ty, 0), 4);
      int rx = min(max(xcc - tx, 0), 19);
      rc[j] = ry * 20 + rx;
    }
    cwb[t] = make_uint2(pack2(w[0], w[1]), pack2(w[2], w[3]));
    rel4[t] = make_uchar4((unsigned char)rc[0], (unsigned char)rc[1],
                          (unsigned char)rc[2], (unsigned char)rc[3]);
  }
  {
    unsigned long long m = __ballot(ok);
    if (lane == 0) wOK[wv] = (m == ~0ull) ? 1 : 0;
  }

  // ---- stage tile: 100 rows x 8 granules = 800 chunks of 16B ----
#pragma unroll
  for (int it = 0; it < 3; ++it) {
    int ch = it * 256 + t;
    int rc = ch >> 3, g = ch & 7;
    int r = rc / 20, cx = rc - r * 20;
    uint4 v = *(const uint4*)(pB + ((size_t)((ty + r) * W_ + tx + cx)) * 64 + g * 8);
    *(uint4*)(tileTb + rc * TSTR + ((g ^ (rc & 7)) << 3)) = v;
  }
  if (t < 32) {
    int ch = 768 + t;
    int rc = ch >> 3, g = ch & 7;
    int r = rc / 20, cx = rc - r * 20;
    uint4 v = *(const uint4*)(pB + ((size_t)((ty + r) * W_ + tx + cx)) * 64 + g * 8);
    *(uint4*)(tileTb + rc * TSTR + ((g ^ (rc & 7)) << 3)) = v;
  }
  __syncthreads();

  bool fast = wOK[0] && wOK[1] && wOK[2] && wOK[3];

  // ---- sampling: 1152 granule-tasks, 4 dense passes + 1 half pass ----
  if (fast) {
    auto do_gran = [&](int n) {
      int job = n >> 3, g = n & 7;
      int jp = job & 15, jk = job >> 4;
      uint2 wp = cwb[job];
      uchar4 rl = rel4[job];
      float w0 = bfl((unsigned short)(wp.x & 0xffffu));
      float w1_ = bfl((unsigned short)(wp.x >> 16));
      float w2_ = bfl((unsigned short)(wp.y & 0xffffu));
      float w3_ = bfl((unsigned short)(wp.y >> 16));
      bf16x8 v0 = *(const bf16x8*)(tileTb + (int)rl.x * TSTR + ((g ^ (rl.x & 7)) << 3));
      bf16x8 v1 = *(const bf16x8*)(tileTb + (int)rl.y * TSTR + ((g ^ (rl.y & 7)) << 3));
      bf16x8 v2 = *(const bf16x8*)(tileTb + (int)rl.z * TSTR + ((g ^ (rl.z & 7)) << 3));
      bf16x8 v3 = *(const bf16x8*)(tileTb + (int)rl.w * TSTR + ((g ^ (rl.w & 7)) << 3));
      const unsigned* u0 = (const unsigned*)&v0;
      const unsigned* u1 = (const unsigned*)&v1;
      const unsigned* u2 = (const unsigned*)&v2;
      const unsigned* u3 = (const unsigned*)&v3;
      unsigned dws[4];
#pragma unroll
      for (int d = 0; d < 4; ++d) {
        f32x2 c0 = {__uint_as_float(u0[d] << 16), __uint_as_float(u0[d] & 0xffff0000u)};
        f32x2 c1 = {__uint_as_float(u1[d] << 16), __uint_as_float(u1[d] & 0xffff0000u)};
        f32x2 c2 = {__uint_as_float(u2[d] << 16), __uint_as_float(u2[d] & 0xffff0000u)};
        f32x2 c3 = {__uint_as_float(u3[d] << 16), __uint_as_float(u3[d] & 0xffff0000u)};
        f32x2 s = w0 * c0 + w1_ * c1 + w2_ * c2 + w3_ * c3;
        dws[d] = pack2(s[0], s[1]);
      }
      *(uint4*)(sAb + jp * ROWS + jk * 64 + g * 8) =
          make_uint4(dws[0], dws[1], dws[2], dws[3]);
    };
    do_gran(t);
    do_gran(t + 256);
    do_gran(t + 512);
    do_gran(t + 768);
    if (t < 128) do_gran(t + 1024);
  } else {
    if (active) {
      int xx = x0 + pixl;
      const unsigned short* ob = offo + (size_t)(b * 18 + kk * 2) * HW_ + y * W_ + xx;
      float offy = bfl(ob[0]);
      float offx = bfl(ob[HW_]);
      float sy = (float)(y + (kk / 3) - 1) + offy;
      float sx = (float)(xx + (kk % 3) - 1) + offx;
      float fy = floorf(sy), fx = floorf(sx);
      float wy = sy - fy, wx = sx - fx;
      int iy = (int)fy, ix = (int)fx;
      float wj[4];
      const unsigned short* pc[4];
#pragma unroll
      for (int j = 0; j < 4; ++j) {
        int dy = j >> 1, dx = j & 1;
        int yc = iy + dy, xc = ix + dx;
        bool v = ((unsigned)yc < 128u) && ((unsigned)xc < 128u);
        int ycc = min(max(yc, 0), 127), xcc = min(max(xc, 0), 127);
        wj[j] = v ? (dy ? wy : 1.f - wy) * (dx ? wx : 1.f - wx) : 0.f;
        pc[j] = pB + ((size_t)(ycc * W_ + xcc)) * 64;
      }
      unsigned short* wr = sAb + pixl * ROWS + kk * 64;
#pragma unroll 4
      for (int c = 0; c < 64; ++c) {
        float v = wj[0] * bfl(pc[0][c]) + wj[1] * bfl(pc[1][c]) +
                  wj[2] * bfl(pc[2][c]) + wj[3] * bfl(pc[3][c]);
        wr[c] = f2bf(v);
      }
    }
  }
  __syncthreads();

  // ---- deform GEMM: 18 slots; 0..8 from preloaded regs, 9..17 from global ----
  f32x4 acc;
  {
    float d = db[o_me];
    acc = (f32x4){d, d, d, d};
  }
  const unsigned short* arow = sAb + l15 * ROWS + (lp << 3);
#define MF(s, bwv)                                                           \
  {                                                                          \
    bf16x8 a = *(const bf16x8*)(arow + (s) * 32);                            \
    acc = __builtin_amdgcn_mfma_f32_16x16x32_bf16(a, (bwv), acc, 0, 0, 0);   \
  }
  MF(0, bwr0) MF(1, bwr1) MF(2, bwr2) MF(3, bwr3) MF(4, bwr4)
  MF(5, bwr5) MF(6, bwr6) MF(7, bwr7) MF(8, bwr8)
#pragma unroll
  for (int s = 9; s < KSLOTS; ++s) {
    bf16x8 a = *(const bf16x8*)(arow + s * 32);
    bf16x8 bw = wfp[(s * 4 + wv) * 64 + lane];
    acc = __builtin_amdgcn_mfma_f32_16x16x32_bf16(a, bw, acc, 0, 0, 0);
  }
#undef MF

#pragma unroll
  for (int j = 0; j < 4; ++j) {
    rTb[(px0 + j) * 72 + o_me] = f2bf(acc[j]);
  }
  __syncthreads();

  // ---- conv1 + BN + ReLU + residual ----
  f32x4 acc1;
  {
    float bb = b1f[o_me];
    acc1 = (f32x4){bb, bb, bb, bb};
  }
  const unsigned short* arow1 = rTb + l15 * 72 + (lp << 3);
  const bf16x8* w1f8 = (const bf16x8*)w1p;
#pragma unroll
  for (int s = 0; s < 2; ++s) {
    bf16x8 a = *(const bf16x8*)(arow1 + s * 32);
    bf16x8 bw = w1f8[(s * 4 + wv) * 64 + lane];
    acc1 = __builtin_amdgcn_mfma_f32_16x16x32_bf16(a, bw, acc1, 0, 0, 0);
  }
  float h0 = fmaxf(acc1[0], 0.f) + xv.x;
  float h1 = fmaxf(acc1[1], 0.f) + xv.y;
  float h2 = fmaxf(acc1[2], 0.f) + xv.z;
  float h3 = fmaxf(acc1[3], 0.f) + xv.w;
  hTb[(px0 + 0) * 72 + o_me] = f2bf(h0);
  hTb[(px0 + 1) * 72 + o_me] = f2bf(h1);
  hTb[(px0 + 2) * 72 + o_me] = f2bf(h2);
  hTb[(px0 + 3) * 72 + o_me] = f2bf(h3);
  __syncthreads();

  // ---- conv2 ----
  f32x4 acc2;
  {
    float bo = b2[o_me];
    acc2 = (f32x4){bo, bo, bo, bo};
  }
  const unsigned short* arow2 = hTb + l15 * 72 + (lp << 3);
  const bf16x8* w2f8 = (const bf16x8*)w2p;
#pragma unroll
  for (int s = 0; s < 2; ++s) {
    bf16x8 a = *(const bf16x8*)(arow2 + s * 32);
    bf16x8 bw = w2f8[(s * 4 + wv) * 64 + lane];
    acc2 = __builtin_amdgcn_mfma_f32_16x16x32_bf16(a, bw, acc2, 0, 0, 0);
  }
  *(float4*)(out + (size_t)(b * C_ + o_me) * HW_ + yx0 + px0) =
      make_float4(acc2[0], acc2[1], acc2[2], acc2[3]);
}

extern "C" void kernel_launch(void* const* d_in, const int* in_sizes, int n_in,
                              void* d_out, int out_size, void* d_ws, size_t ws_size,
                              hipStream_t stream) {
  const float* x = (const float*)d_in[0];
  const float* offw = (const float*)d_in[1];
  const float* offb = (const float*)d_in[2];
  const float* dw = (const float*)d_in[3];
  const float* db = (const float*)d_in[4];
  const float* w1 = (const float*)d_in[5];
  const float* b1 = (const float*)d_in[6];
  const float* gamma = (const float*)d_in[7];
  const float* beta = (const float*)d_in[8];
  const float* rmean = (const float*)d_in[9];
  const float* rvar = (const float*)d_in[10];
  const float* w2 = (const float*)d_in[11];
  const float* b2 = (const float*)d_in[12];
  float* out = (float*)d_out;

  unsigned short* pbf = (unsigned short*)d_ws;      // 8388608 bf16 (NHWC)
  unsigned short* offo = pbf + 8388608;             // 2359296 bf16
  unsigned short* wf2 = offo + 2359296;             // 36864 bf16
  unsigned short* offwp = wf2 + 36864;              // 18432 bf16
  unsigned short* w1p = offwp + 18432;              // 4096 bf16
  unsigned short* w2p = w1p + 4096;                 // 4096 bf16
  float* b1f = (float*)(w2p + 4096);                // 64 f

  pool_prep_kernel<<<2305, 256, 0, stream>>>(x, pbf, dw, offw, w1, b1, gamma,
                                             beta, rmean, rvar, w2, wf2, offwp,
                                             w1p, w2p, b1f);
  offconv_kernel<<<2048, 256, 0, stream>>>(pbf, offwp, offb, offo);
  deform_kernel<<<8192, 256, 0, stream>>>(pbf, offo, wf2, w1p, w2p, db, b1f, b2,
                                          x, out);
}